// Round 12
// baseline (238.209 us; speedup 1.0000x reference)
//
#include <hip/hip_runtime.h>
#include <hip/hip_fp16.h>
#include <stdint.h>

typedef __attribute__((ext_vector_type(8))) short short8;
typedef __attribute__((ext_vector_type(16))) float f32x16;
typedef unsigned int u32;
typedef unsigned long long u64;

#define DEVI __device__ __forceinline__

constexpr int S_ = 2048, D_ = 128, BH_ = 64;
constexpr int KVB = 32, NT = S_ / KVB;                    // 64 kv tiles
constexpr size_t IMG_T   = 16384;                         // per (bh,tile): K 8KB + VT 8KB
constexpr size_t IMG_ALL = (size_t)BH_ * NT * IMG_T;      // 64 MB
constexpr size_t MOFF    = IMG_ALL;                       // row-order f32 BIAS (0 / -30000)
constexpr size_t WS_NEED = MOFF + (size_t)BH_ * S_ * 4 + 1024;

// pack two f32 -> two f16 in one u32 (lo=a, hi=b)
DEVI u32 pkh(float a, float b){
  u32 la = (u32)__half_as_ushort(__float2half(a));
  u32 lb = (u32)__half_as_ushort(__float2half(b));
  return la | (lb << 16);
}

DEVI f32x16 zero16(){
  f32x16 z;
#pragma unroll
  for (int i = 0; i < 16; ++i) z[i] = 0.0f;
  return z;
}

// native exp2: v_exp_f32 computes 2^x (single trans-pipe instruction)
DEVI float ex2(float x){
  float r;
  asm("v_exp_f32 %0, %1" : "=v"(r) : "v"(x));
  return r;
}

#define GLOAD16(gsrc, ldst) \
  __builtin_amdgcn_global_load_lds((const __attribute__((address_space(1))) u32*)(gsrc), \
                                   (__attribute__((address_space(3))) u32*)(ldst), 16, 0, 0)
#define GLOAD4(gsrc, ldst) \
  __builtin_amdgcn_global_load_lds((const __attribute__((address_space(1))) u32*)(gsrc), \
                                   (__attribute__((address_space(3))) u32*)(ldst), 4, 0, 0)

// ============================ PRE-PASS ============================
// Per (bh, 32-row tile): K fragment image [k8=0..15][row=0..31] 16B chunks
// (chunk = f16 K[row][k8*8..+8]); VT image [v8=0..3][d=0..127] 16B chunks
// (chunk = f16 V[kv0+v8*8+j][d], j=0..7). Plus row-order f32 BIAS values
// (0 unmasked / -30000 masked) used as the QK MFMA C-initializer.
__global__ __launch_bounds__(256)
void sdpa_prepass(const float* __restrict__ Kg, const float* __restrict__ Vg,
                  const int* __restrict__ Mg, char* __restrict__ ws)
{
  __shared__ float T[32][133];
  const int tid = threadIdx.x;
  const int bh = blockIdx.x >> 6, t = blockIdx.x & 63;
  const int kv0 = t * KVB;
  char* img = ws + (size_t)(bh * NT + t) * IMG_T;
  const int r  = tid >> 3;        // 0..31 kv row
  const int c8 = tid & 7;         // 16-float column chunk

  { // K: direct convert
    const float* src = Kg + ((size_t)bh * S_ + kv0 + r) * D_ + c8 * 16;
    float4 a = ((const float4*)src)[0];
    float4 b = ((const float4*)src)[1];
    float4 c = ((const float4*)src)[2];
    float4 d = ((const float4*)src)[3];
    uint4 o0, o1;
    o0.x = pkh(a.x,a.y); o0.y = pkh(a.z,a.w); o0.z = pkh(b.x,b.y); o0.w = pkh(b.z,b.w);
    o1.x = pkh(c.x,c.y); o1.y = pkh(c.z,c.w); o1.z = pkh(d.x,d.y); o1.w = pkh(d.z,d.w);
    *(uint4*)(img + (c8*2 + 0)*512 + r*16) = o0;
    *(uint4*)(img + (c8*2 + 1)*512 + r*16) = o1;
  }

  { // V: LDS transpose
    const float* src = Vg + ((size_t)bh * S_ + kv0 + r) * D_ + c8 * 16;
    float4 a = ((const float4*)src)[0];
    float4 b = ((const float4*)src)[1];
    float4 c = ((const float4*)src)[2];
    float4 d = ((const float4*)src)[3];
    float x[16] = {a.x,a.y,a.z,a.w,b.x,b.y,b.z,b.w,c.x,c.y,c.z,c.w,d.x,d.y,d.z,d.w};
#pragma unroll
    for (int i = 0; i < 16; ++i) T[r][c8*16 + i] = x[i];
  }
  __syncthreads();
#pragma unroll
  for (int cc = 0; cc < 2; ++cc){
    int ch = cc*256 + tid;              // 0..511
    int v8 = ch >> 7, d = ch & 127;
    float y[8];
#pragma unroll
    for (int j = 0; j < 8; ++j) y[j] = T[v8*8 + j][d];
    uint4 o;
    o.x = pkh(y[0],y[1]); o.y = pkh(y[2],y[3]); o.z = pkh(y[4],y[5]); o.w = pkh(y[6],y[7]);
    *(uint4*)(img + 8192 + ch*16) = o;
  }

  if (t == 0){ // row-order bias values
    float* Mf = (float*)(ws + MOFF) + (size_t)bh * S_;
    for (int i = tid; i < S_; i += 256)
      Mf[i] = (Mg[(size_t)bh * S_ + i] != 0) ? 0.0f : -30000.0f;
  }
}

// ============================ MAIN ============================
// grid 1024 (bh-clustered per XCD), 256 thr = 4 waves x 32 q rows.
// KVB=32, ring-2 LDS (33 KB), __launch_bounds__(256,3): 3 independent
// blocks/CU = 3 waves/SIMD from 3 separate barrier groups — one block's
// barrier stall is covered by the other two. Bias-C-init; native v_exp_f32.
__global__ __launch_bounds__(256, 3)
void sdpa_main(const float* __restrict__ Qg, const char* __restrict__ ws,
               float* __restrict__ Og)
{
  __shared__ __align__(16) char Buf[2][16384];
  __shared__ __align__(16) float Bb[2][64];

  const int tid  = threadIdx.x;
  const int lane = tid & 63;
  const int wv   = tid >> 6;          // 0..3
  const int h    = lane >> 5;
  const int r31  = lane & 31;

  // same-bh blocks clustered per XCD (r6-proven: 66 MB FETCH)
  const int bi  = blockIdx.x;
  const int xcd = bi & 7, rr2 = bi >> 3;
  const int qb  = rr2 & 15, bhl = rr2 >> 4;
  const int bh  = xcd*8 + bhl;

  const char*  img0 = ws + (size_t)bh * NT * IMG_T;
  const float* Mf   = (const float*)(ws + MOFF) + (size_t)bh * S_;
  const float* Qh   = Qg + (size_t)bh * S_ * D_;
  float*       Oh   = Og + (size_t)bh * S_ * D_;

  const int q0 = qb*128 + wv*32 + r31;

  auto STAGE = [&](int tt, int bufi){   // stage one 16 KB image + bias
    const char* g = img0 + (size_t)tt * IMG_T;
#pragma unroll
    for (int j = 0; j < 4; ++j){
      int ch = wv*4 + j;
      GLOAD16(g + ch*1024 + lane*16, &Buf[bufi][ch*1024]);
    }
    GLOAD4(Mf + tt*32 + lane, &Bb[bufi][0]);   // 32 valid + 32 slack
  };

  // ---- Q loads first (first __syncthreads drains them too) ----
  float4 qa[8], qb_[8];
#pragma unroll
  for (int df = 0; df < 8; ++df){
    const float* p0 = Qh + (size_t)q0 * D_ + df*16 + h*8;
    qa[df]  = *(const float4*)(p0);
    qb_[df] = *(const float4*)(p0 + 4);
  }
  STAGE(0, 0);

  // f16 B-operand, log2(e) folded (softmax in exp2 domain)
  constexpr float L2E = 1.44269504088896f;
  short8 qs[8];
#pragma unroll
  for (int df = 0; df < 8; ++df){
    union { u32 u[4]; short8 s; } cv;
    cv.u[0] = pkh(qa[df].x*L2E,  qa[df].y*L2E);
    cv.u[1] = pkh(qa[df].z*L2E,  qa[df].w*L2E);
    cv.u[2] = pkh(qb_[df].x*L2E, qb_[df].y*L2E);
    cv.u[3] = pkh(qb_[df].z*L2E, qb_[df].w*L2E);
    qs[df] = cv.s;
  }

  f32x16 accO[4];
#pragma unroll
  for (int dn = 0; dn < 4; ++dn) accO[dn] = zero16();
  float mrun = -INFINITY, lrun = 0.0f;

  for (int t = 0; t < NT; ++t){
    const int buf = t & 1;
    __syncthreads();                    // fenced: drains vmcnt+lgkm, barrier
    if (t + 1 < NT) STAGE(t + 1, buf ^ 1);

    const char* base = Buf[buf];

    // ---- sa init = mask bias (replaces zero-init AND mask multiply) ----
    f32x16 sa;
#pragma unroll
    for (int rb = 0; rb < 4; ++rb){
      float4 bv = *(const float4*)&Bb[buf][rb*8 + h*4];
      sa[rb*4+0] = bv.x; sa[rb*4+1] = bv.y; sa[rb*4+2] = bv.z; sa[rb*4+3] = bv.w;
    }

    // ---- QK^T (swapped): S^T[kv][q] = K * Q^T ----
    __builtin_amdgcn_s_setprio(1);
#pragma unroll
    for (int df = 0; df < 8; ++df){
      short8 kf = *(const short8*)(base + ((df*2 + h) << 9) + (r31 << 4));
      sa = __builtin_amdgcn_mfma_f32_32x32x16_f16(kf, qs[df], sa, 0, 0, 0);
    }
    __builtin_amdgcn_s_setprio(0);

    // ---- online softmax, exp2 domain ----
    float m01 = fmaxf(sa[0], sa[1]),  m23 = fmaxf(sa[2], sa[3]);
    float m45 = fmaxf(sa[4], sa[5]),  m67 = fmaxf(sa[6], sa[7]);
    float m89 = fmaxf(sa[8], sa[9]),  mab = fmaxf(sa[10], sa[11]);
    float mcd = fmaxf(sa[12], sa[13]), mef = fmaxf(sa[14], sa[15]);
    float pmax = fmaxf(fmaxf(fmaxf(m01,m23), fmaxf(m45,m67)),
                       fmaxf(fmaxf(m89,mab), fmaxf(mcd,mef)));
    pmax = fmaxf(pmax, __shfl_xor(pmax, 32, 64));
    if (!__all(pmax - mrun <= 8.0f)){          // T13 defer-rescale
      float mnew = fmaxf(mrun, pmax);
      float sc = ex2(mrun - mnew);
      lrun *= sc;
#pragma unroll
      for (int dn = 0; dn < 4; ++dn)
#pragma unroll
        for (int i = 0; i < 16; ++i) accO[dn][i] *= sc;
      mrun = mnew;
    }
    float ps0 = 0.f, ps1 = 0.f, ps2 = 0.f, ps3 = 0.f;
#pragma unroll
    for (int rb = 0; rb < 4; ++rb){
      float e0 = ex2(sa[rb*4+0] - mrun);
      float e1 = ex2(sa[rb*4+1] - mrun);
      float e2 = ex2(sa[rb*4+2] - mrun);
      float e3 = ex2(sa[rb*4+3] - mrun);
      sa[rb*4+0]=e0; sa[rb*4+1]=e1; sa[rb*4+2]=e2; sa[rb*4+3]=e3;
      ps0 += e0; ps1 += e1; ps2 += e2; ps3 += e3;
    }
    float psum = (ps0 + ps1) + (ps2 + ps3);
    psum += __shfl_xor(psum, 32, 64);
    lrun += psum;

    // ---- P fragments: C-layout -> B-operand, 2 shfl + selects per kf ----
    short8 pf8[2];
#pragma unroll
    for (int kf = 0; kf < 2; ++kf){
      const int o = kf*8;
      u32 w0 = pkh(sa[o+0], sa[o+1]);
      u32 w1 = pkh(sa[o+2], sa[o+3]);
      u32 w2 = pkh(sa[o+4], sa[o+5]);
      u32 w3 = pkh(sa[o+6], sa[o+7]);
      u32 x0 = __shfl_xor(h ? w0 : w2, 32, 64);
      u32 x1 = __shfl_xor(h ? w1 : w3, 32, 64);
      union { u32 u[4]; short8 s; } cv;
      cv.u[0] = h ? x0 : w0;
      cv.u[1] = h ? x1 : w1;
      cv.u[2] = h ? w2 : x0;
      cv.u[3] = h ? w3 : x1;
      pf8[kf] = cv.s;
    }

    // ---- PV: O^T[d][q] += V^T * P^T ----
    __builtin_amdgcn_s_setprio(1);
#pragma unroll
    for (int dn = 0; dn < 4; ++dn){
      const int co = (dn*32 + r31) << 4;
      short8 v0 = *(const short8*)(base + 8192 + (h << 11)       + co);
      short8 v1 = *(const short8*)(base + 8192 + ((2 + h) << 11) + co);
      accO[dn] = __builtin_amdgcn_mfma_f32_32x32x16_f16(v0, pf8[0], accO[dn], 0, 0, 0);
      accO[dn] = __builtin_amdgcn_mfma_f32_32x32x16_f16(v1, pf8[1], accO[dn], 0, 0, 0);
    }
    __builtin_amdgcn_s_setprio(0);
  }

  // ---- epilogue ----
  const float inv = 1.0f / lrun;
  float* Orow = Oh + (size_t)q0 * D_;
#pragma unroll
  for (int dn = 0; dn < 4; ++dn){
#pragma unroll
    for (int rb = 0; rb < 4; ++rb){
      float4 o4;
      o4.x = accO[dn][rb*4+0]*inv;
      o4.y = accO[dn][rb*4+1]*inv;
      o4.z = accO[dn][rb*4+2]*inv;
      o4.w = accO[dn][rb*4+3]*inv;
      *(float4*)&Orow[dn*32 + rb*8 + h*4] = o4;
    }
  }
}

// ============================ FALLBACK (if ws too small) ============================
DEVI void sync_lds(){
  asm volatile("s_waitcnt lgkmcnt(0)" ::: "memory");
  __builtin_amdgcn_s_barrier();
}
#define TR_READ(dst, addr, IMM) \
  asm volatile("ds_read_b64_tr_b16 %0, %1 offset:" IMM : "=v"(dst) : "v"(addr))

__global__ __launch_bounds__(256, 2)
void sdpa_fallback(const float* __restrict__ Qg, const float* __restrict__ Kg,
                   const float* __restrict__ Vg, const int* __restrict__ Mg,
                   float* __restrict__ Og)
{
  constexpr int S = 2048, D = 128;
  __shared__ __align__(16) short Klds[64*136];
  __shared__ __align__(16) short Vlds[64*128];
  __shared__ __align__(16) float Mlds[64];

  const int tid  = threadIdx.x;
  const int lane = tid & 63;
  const int wv   = tid >> 6;
  const int h    = lane >> 5;
  const int r31  = lane & 31;
  const int r15  = lane & 15;
  const int b4   = (lane >> 4) & 1;
  const int srow = tid >> 5;
  const int scol = tid & 31;

  const int bh = blockIdx.x >> 4;
  const int qb = blockIdx.x & 15;

  const float* Qh = Qg + (size_t)bh * S * D;
  const float* Kh = Kg + (size_t)bh * S * D;
  const float* Vh = Vg + (size_t)bh * S * D;
  const int*   Mh = Mg + (size_t)bh * S;
  float*       Oh = Og + (size_t)bh * S * D;

  const int q0 = qb*128 + wv*32 + r31;

  short8 qs[8];
#pragma unroll
  for (int df = 0; df < 8; ++df){
    const float* p0 = Qh + (size_t)q0 * D + df*16 + h*8;
    float4 a = *(const float4*)(p0);
    float4 b = *(const float4*)(p0 + 4);
    union { u32 u[4]; short8 s; } cv;
    cv.u[0] = pkh(a.x, a.y); cv.u[1] = pkh(a.z, a.w);
    cv.u[2] = pkh(b.x, b.y); cv.u[3] = pkh(b.z, b.w);
    qs[df] = cv.s;
  }

  float4 kr[8], vr[8];
  int mpre = 1;
#pragma unroll
  for (int p = 0; p < 8; ++p){
    int row = p*8 + srow;
    kr[p] = *(const float4*)&Kh[(size_t)row * D + scol*4];
    vr[p] = *(const float4*)&Vh[(size_t)row * D + scol*4];
  }
  if (tid < 64) mpre = Mh[tid];

  f32x16 accO[4];
#pragma unroll
  for (int dn = 0; dn < 4; ++dn) accO[dn] = zero16();
  float mrun = -INFINITY, lrun = 0.0f;

  const u32 vbase = (u32)(size_t)(&Vlds[0]) + (u32)(h*2048 + b4*128 + r15*8);

  for (int t = 0; t < 32; ++t){
#pragma unroll
    for (int p = 0; p < 8; ++p){
      int row = p*8 + srow;
      u32 k0 = pkh(kr[p].x, kr[p].y), k1 = pkh(kr[p].z, kr[p].w);
      *(u64*)&Klds[row*136 + scol*4] = ((u64)k1 << 32) | k0;
      u32 v0 = pkh(vr[p].x, vr[p].y), v1 = pkh(vr[p].z, vr[p].w);
      int E = (row >> 2)*512 + (scol >> 2)*64 + (row & 3)*16 + (scol & 3)*4;
      *(u64*)&Vlds[E] = ((u64)v1 << 32) | v0;
    }
    if (tid < 64) Mlds[tid] = (mpre != 0) ? 1.0f : 0.0f;

    if (t < 31){
      const int kv0 = (t+1)*64;
#pragma unroll
      for (int p = 0; p < 8; ++p){
        int row = kv0 + p*8 + srow;
        kr[p] = *(const float4*)&Kh[(size_t)row * D + scol*4];
        vr[p] = *(const float4*)&Vh[(size_t)row * D + scol*4];
      }
      if (tid < 64) mpre = Mh[kv0 + tid];
    }

    sync_lds();

    f32x16 sa[2];
    sa[0] = zero16(); sa[1] = zero16();
#pragma unroll
    for (int mf = 0; mf < 2; ++mf){
#pragma unroll
      for (int df = 0; df < 8; ++df){
        short8 kf8 = *(const short8*)&Klds[(mf*32 + r31)*136 + df*16 + h*8];
        sa[mf] = __builtin_amdgcn_mfma_f32_32x32x16_f16(kf8, qs[df], sa[mf], 0, 0, 0);
      }
    }

    float pmax = -3.0e38f;
#pragma unroll
    for (int mf = 0; mf < 2; ++mf)
#pragma unroll
      for (int i = 0; i < 16; ++i) pmax = fmaxf(pmax, sa[mf][i]);
    pmax = fmaxf(pmax, __shfl_xor(pmax, 32, 64));
    const float mnew  = fmaxf(mrun, pmax);
    const float scale = __expf(mrun - mnew);
    float psum = 0.0f;
#pragma unroll
    for (int mf = 0; mf < 2; ++mf){
#pragma unroll
      for (int rb = 0; rb < 4; ++rb){
        float4 mv = *(const float4*)&Mlds[mf*32 + rb*8 + h*4];
        float mva[4] = {mv.x, mv.y, mv.z, mv.w};
#pragma unroll
        for (int i = 0; i < 4; ++i){
          float e = __expf(sa[mf][rb*4 + i] - mnew) * mva[i];
          sa[mf][rb*4 + i] = e;
          psum += e;
        }
      }
    }
    psum += __shfl_xor(psum, 32, 64);
    lrun = lrun * scale + psum;
    mrun = mnew;
#pragma unroll
    for (int dn = 0; dn < 4; ++dn)
#pragma unroll
      for (int i = 0; i < 16; ++i) accO[dn][i] *= scale;

    short8 pf8[4];
#pragma unroll
    for (int kf = 0; kf < 4; ++kf){
      const int mf = kf >> 1, o = (kf & 1)*8;
      u32 w0 = pkh(sa[mf][o+0], sa[mf][o+1]);
      u32 w1 = pkh(sa[mf][o+2], sa[mf][o+3]);
      u32 w2 = pkh(sa[mf][o+4], sa[mf][o+5]);
      u32 w3 = pkh(sa[mf][o+6], sa[mf][o+7]);
      u32 s0 = __shfl_xor(w0, 32, 64);
      u32 s1 = __shfl_xor(w1, 32, 64);
      u32 s2 = __shfl_xor(w2, 32, 64);
      u32 s3 = __shfl_xor(w3, 32, 64);
      union { u32 u[4]; short8 s; } cv;
      cv.u[0] = h ? s2 : w0;
      cv.u[1] = h ? s3 : w1;
      cv.u[2] = h ? w2 : s0;
      cv.u[3] = h ? w3 : s1;
      pf8[kf] = cv.s;
    }

#pragma unroll
    for (int dn = 0; dn < 4; ++dn){
      u32 vdn = vbase + dn*256;
      u64 ta0, ta1, tb0, tb1, tc0, tc1, td0, td1;
      TR_READ(ta0, vdn, "0");     TR_READ(ta1, vdn, "1024");
      TR_READ(tb0, vdn, "4096");  TR_READ(tb1, vdn, "5120");
      TR_READ(tc0, vdn, "8192");  TR_READ(tc1, vdn, "9216");
      TR_READ(td0, vdn, "12288"); TR_READ(td1, vdn, "13312");
      asm volatile("s_waitcnt lgkmcnt(0)" ::: "memory");
      __builtin_amdgcn_sched_barrier(0);
      union { u64 q[2]; short8 s; } fa, fb, fc, fd;
      fa.q[0] = ta0; fa.q[1] = ta1;
      fb.q[0] = tb0; fb.q[1] = tb1;
      fc.q[0] = tc0; fc.q[1] = tc1;
      fd.q[0] = td0; fd.q[1] = td1;
      accO[dn] = __builtin_amdgcn_mfma_f32_32x32x16_f16(fa.s, pf8[0], accO[dn], 0,0,0);
      accO[dn] = __builtin_amdgcn_mfma_f32_32x32x16_f16(fb.s, pf8[1], accO[dn], 0,0,0);
      accO[dn] = __builtin_amdgcn_mfma_f32_32x32x16_f16(fc.s, pf8[2], accO[dn], 0,0,0);
      accO[dn] = __builtin_amdgcn_mfma_f32_32x32x16_f16(fd.s, pf8[3], accO[dn], 0,0,0);
    }

    sync_lds();
  }

  const float inv = 1.0f / lrun;
  float* Orow = Oh + (size_t)q0 * D;
#pragma unroll
  for (int dn = 0; dn < 4; ++dn){
#pragma unroll
    for (int rb = 0; rb < 4; ++rb){
      float4 o4;
      o4.x = accO[dn][rb*4+0]*inv;
      o4.y = accO[dn][rb*4+1]*inv;
      o4.z = accO[dn][rb*4+2]*inv;
      o4.w = accO[dn][rb*4+3]*inv;
      *(float4*)&Orow[dn*32 + rb*8 + h*4] = o4;
    }
  }
}

extern "C" void kernel_launch(void* const* d_in, const int* in_sizes, int n_in,
                              void* d_out, int out_size, void* d_ws, size_t ws_size,
                              hipStream_t stream) {
  const float* q = (const float*)d_in[0];
  const float* k = (const float*)d_in[1];
  const float* v = (const float*)d_in[2];
  const int*   m = (const int*)d_in[3];
  float* out = (float*)d_out;
  if (ws_size >= WS_NEED){
    sdpa_prepass<<<dim3(BH_ * NT), dim3(256), 0, stream>>>(k, v, m, (char*)d_ws);
    sdpa_main<<<dim3(1024), dim3(256), 0, stream>>>(q, (const char*)d_ws, out);
  } else {
    sdpa_fallback<<<dim3(1024), dim3(256), 0, stream>>>(q, k, v, m, out);
  }
}

// Round 14
// 218.440 us; speedup vs baseline: 1.0905x; 1.0905x over previous
//
#include <hip/hip_runtime.h>
#include <hip/hip_fp16.h>
#include <stdint.h>

typedef __attribute__((ext_vector_type(8))) short short8;
typedef __attribute__((ext_vector_type(16))) float f32x16;
typedef unsigned int u32;
typedef unsigned long long u64;

#define DEVI __device__ __forceinline__

constexpr int S_ = 2048, D_ = 128, BH_ = 64;
constexpr int KVB = 32, NT = S_ / KVB;                    // 64 kv tiles
constexpr size_t IMG_T   = 16384;                         // per (bh,tile): K 8KB + VT 8KB
constexpr size_t IMG_ALL = (size_t)BH_ * NT * IMG_T;      // 64 MB
constexpr size_t MOFF    = IMG_ALL;                       // row-order f32 BIAS (0 / -30000)
constexpr size_t WS_NEED = MOFF + (size_t)BH_ * S_ * 4 + 1024;

// pack two f32 -> two f16 in one u32 (lo=a, hi=b)
DEVI u32 pkh(float a, float b){
  u32 la = (u32)__half_as_ushort(__float2half(a));
  u32 lb = (u32)__half_as_ushort(__float2half(b));
  return la | (lb << 16);
}

DEVI f32x16 zero16(){
  f32x16 z;
#pragma unroll
  for (int i = 0; i < 16; ++i) z[i] = 0.0f;
  return z;
}

// native exp2: v_exp_f32 computes 2^x (single trans-pipe instruction)
DEVI float ex2(float x){
  float r;
  asm("v_exp_f32 %0, %1" : "=v"(r) : "v"(x));
  return r;
}
// 3-input max, single VOP3
DEVI float mx3(float a, float b, float c){
  float r;
  asm("v_max3_f32 %0, %1, %2, %3" : "=v"(r) : "v"(a), "v"(b), "v"(c));
  return r;
}

#define GLOAD16(gsrc, ldst) \
  __builtin_amdgcn_global_load_lds((const __attribute__((address_space(1))) u32*)(gsrc), \
                                   (__attribute__((address_space(3))) u32*)(ldst), 16, 0, 0)
#define GLOAD4(gsrc, ldst) \
  __builtin_amdgcn_global_load_lds((const __attribute__((address_space(1))) u32*)(gsrc), \
                                   (__attribute__((address_space(3))) u32*)(ldst), 4, 0, 0)

// ============================ PRE-PASS ============================
// Per (bh, 32-row tile): K fragment image [k8=0..15][row=0..31] 16B chunks
// (chunk = f16 K[row][k8*8..+8]); VT image [v8=0..3][d=0..127] 16B chunks
// (chunk = f16 V[kv0+v8*8+j][d], j=0..7). Plus row-order f32 BIAS values
// (0 unmasked / -30000 masked) used as the QK MFMA C-initializer.
__global__ __launch_bounds__(256)
void sdpa_prepass(const float* __restrict__ Kg, const float* __restrict__ Vg,
                  const int* __restrict__ Mg, char* __restrict__ ws)
{
  __shared__ float T[32][133];
  const int tid = threadIdx.x;
  const int bh = blockIdx.x >> 6, t = blockIdx.x & 63;
  const int kv0 = t * KVB;
  char* img = ws + (size_t)(bh * NT + t) * IMG_T;
  const int r  = tid >> 3;        // 0..31 kv row
  const int c8 = tid & 7;         // 16-float column chunk

  { // K: direct convert
    const float* src = Kg + ((size_t)bh * S_ + kv0 + r) * D_ + c8 * 16;
    float4 a = ((const float4*)src)[0];
    float4 b = ((const float4*)src)[1];
    float4 c = ((const float4*)src)[2];
    float4 d = ((const float4*)src)[3];
    uint4 o0, o1;
    o0.x = pkh(a.x,a.y); o0.y = pkh(a.z,a.w); o0.z = pkh(b.x,b.y); o0.w = pkh(b.z,b.w);
    o1.x = pkh(c.x,c.y); o1.y = pkh(c.z,c.w); o1.z = pkh(d.x,d.y); o1.w = pkh(d.z,d.w);
    *(uint4*)(img + (c8*2 + 0)*512 + r*16) = o0;
    *(uint4*)(img + (c8*2 + 1)*512 + r*16) = o1;
  }

  { // V: LDS transpose
    const float* src = Vg + ((size_t)bh * S_ + kv0 + r) * D_ + c8 * 16;
    float4 a = ((const float4*)src)[0];
    float4 b = ((const float4*)src)[1];
    float4 c = ((const float4*)src)[2];
    float4 d = ((const float4*)src)[3];
    float x[16] = {a.x,a.y,a.z,a.w,b.x,b.y,b.z,b.w,c.x,c.y,c.z,c.w,d.x,d.y,d.z,d.w};
#pragma unroll
    for (int i = 0; i < 16; ++i) T[r][c8*16 + i] = x[i];
  }
  __syncthreads();
#pragma unroll
  for (int cc = 0; cc < 2; ++cc){
    int ch = cc*256 + tid;              // 0..511
    int v8 = ch >> 7, d = ch & 127;
    float y[8];
#pragma unroll
    for (int j = 0; j < 8; ++j) y[j] = T[v8*8 + j][d];
    uint4 o;
    o.x = pkh(y[0],y[1]); o.y = pkh(y[2],y[3]); o.z = pkh(y[4],y[5]); o.w = pkh(y[6],y[7]);
    *(uint4*)(img + 8192 + ch*16) = o;
  }

  if (t == 0){ // row-order bias values
    float* Mf = (float*)(ws + MOFF) + (size_t)bh * S_;
    for (int i = tid; i < S_; i += 256)
      Mf[i] = (Mg[(size_t)bh * S_ + i] != 0) ? 0.0f : -30000.0f;
  }
}

// ============================ MAIN ============================
// grid 512 (bh-clustered per XCD), 256 thr = 4 waves x 64 q rows (two 32-col
// groups A/B sharing every K/V fragment read -> LDS traffic per work halved).
// KVB=32, ring-2 LDS (33 KB), __syncthreads per unit; bias-C-init; v_exp_f32.
__global__ __launch_bounds__(256, 2)
void sdpa_main(const float* __restrict__ Qg, const char* __restrict__ ws,
               float* __restrict__ Og)
{
  __shared__ __align__(16) char Buf[2][16384];
  __shared__ __align__(16) float Bb[2][64];

  const int tid  = threadIdx.x;
  const int lane = tid & 63;
  const int wv   = tid >> 6;          // 0..3
  const int h    = lane >> 5;
  const int r31  = lane & 31;

  // same-bh blocks clustered per XCD: 512 = 8 xcd x (8 qb x 8 bhl)
  const int bi  = blockIdx.x;
  const int xcd = bi & 7, rr2 = bi >> 3;
  const int qb  = rr2 & 7, bhl = rr2 >> 3;
  const int bh  = xcd*8 + bhl;

  const char*  img0 = ws + (size_t)bh * NT * IMG_T;
  const float* Mf   = (const float*)(ws + MOFF) + (size_t)bh * S_;
  const float* Qh   = Qg + (size_t)bh * S_ * D_;
  float*       Oh   = Og + (size_t)bh * S_ * D_;

  const int qA = qb*256 + wv*64 + r31;   // group A row; group B = qA + 32

  auto STAGE = [&](int tt, int bufi){    // stage one 16 KB image + bias
    const char* g = img0 + (size_t)tt * IMG_T;
#pragma unroll
    for (int j = 0; j < 4; ++j){
      int ch = wv*4 + j;
      GLOAD16(g + ch*1024 + lane*16, &Buf[bufi][ch*1024]);
    }
    GLOAD4(Mf + tt*32 + lane, &Bb[bufi][0]);   // 32 valid + 32 slack
  };

  // ---- Q loads first (first __syncthreads drains them too) ----
  float4 qaA[8], qbA[8], qaB[8], qbB[8];
#pragma unroll
  for (int df = 0; df < 8; ++df){
    const float* pA = Qh + (size_t)qA * D_ + df*16 + h*8;
    const float* pB = Qh + (size_t)(qA + 32) * D_ + df*16 + h*8;
    qaA[df] = *(const float4*)(pA);  qbA[df] = *(const float4*)(pA + 4);
    qaB[df] = *(const float4*)(pB);  qbB[df] = *(const float4*)(pB + 4);
  }
  STAGE(0, 0);

  // f16 B-operand, log2(e) folded (softmax in exp2 domain)
  constexpr float L2E = 1.44269504088896f;
  short8 qsA[8], qsB[8];
#pragma unroll
  for (int df = 0; df < 8; ++df){
    union { u32 u[4]; short8 s; } ca, cb;
    ca.u[0] = pkh(qaA[df].x*L2E, qaA[df].y*L2E);
    ca.u[1] = pkh(qaA[df].z*L2E, qaA[df].w*L2E);
    ca.u[2] = pkh(qbA[df].x*L2E, qbA[df].y*L2E);
    ca.u[3] = pkh(qbA[df].z*L2E, qbA[df].w*L2E);
    cb.u[0] = pkh(qaB[df].x*L2E, qaB[df].y*L2E);
    cb.u[1] = pkh(qaB[df].z*L2E, qaB[df].w*L2E);
    cb.u[2] = pkh(qbB[df].x*L2E, qbB[df].y*L2E);
    cb.u[3] = pkh(qbB[df].z*L2E, qbB[df].w*L2E);
    qsA[df] = ca.s; qsB[df] = cb.s;
  }

  f32x16 accA[4], accB[4];
#pragma unroll
  for (int dn = 0; dn < 4; ++dn){ accA[dn] = zero16(); accB[dn] = zero16(); }
  float mrA = -INFINITY, lrA = 0.0f, mrB = -INFINITY, lrB = 0.0f;

  // softmax + P-pack for one group (bias pre-added via C-init; exp2 domain)
#define SOFT(SA_, MR_, LR_, ACC_, PF_) do {                                    \
    float t0 = mx3(SA_[0], SA_[1], SA_[2]);                                    \
    float t1 = mx3(SA_[3], SA_[4], SA_[5]);                                    \
    float t2 = mx3(SA_[6], SA_[7], SA_[8]);                                    \
    float t3 = mx3(SA_[9], SA_[10], SA_[11]);                                  \
    float t4 = mx3(SA_[12], SA_[13], SA_[14]);                                 \
    float pmax = fmaxf(mx3(t0, t1, t2), mx3(t3, t4, SA_[15]));                 \
    pmax = fmaxf(pmax, __shfl_xor(pmax, 32, 64));                              \
    if (!__all(pmax - MR_ <= 12.0f)){                                          \
      float mnew = fmaxf(MR_, pmax);                                           \
      float sc = ex2(MR_ - mnew);                                              \
      LR_ *= sc;                                                               \
      _Pragma("unroll")                                                        \
      for (int dn = 0; dn < 4; ++dn)                                           \
        _Pragma("unroll")                                                      \
        for (int i = 0; i < 16; ++i) ACC_[dn][i] *= sc;                        \
      MR_ = mnew;                                                              \
    }                                                                          \
    float ps0 = 0.f, ps1 = 0.f, ps2 = 0.f, ps3 = 0.f;                          \
    _Pragma("unroll")                                                          \
    for (int rb = 0; rb < 4; ++rb){                                            \
      float e0 = ex2(SA_[rb*4+0] - MR_);                                       \
      float e1 = ex2(SA_[rb*4+1] - MR_);                                       \
      float e2 = ex2(SA_[rb*4+2] - MR_);                                       \
      float e3 = ex2(SA_[rb*4+3] - MR_);                                       \
      SA_[rb*4+0]=e0; SA_[rb*4+1]=e1; SA_[rb*4+2]=e2; SA_[rb*4+3]=e3;          \
      ps0 += e0; ps1 += e1; ps2 += e2; ps3 += e3;                              \
    }                                                                          \
    float psum = (ps0 + ps1) + (ps2 + ps3);                                    \
    psum += __shfl_xor(psum, 32, 64);                                          \
    LR_ += psum;                                                               \
    _Pragma("unroll")                                                          \
    for (int kf = 0; kf < 2; ++kf){                                            \
      const int o = kf*8;                                                      \
      u32 w0 = pkh(SA_[o+0], SA_[o+1]);                                        \
      u32 w1 = pkh(SA_[o+2], SA_[o+3]);                                        \
      u32 w2 = pkh(SA_[o+4], SA_[o+5]);                                        \
      u32 w3 = pkh(SA_[o+6], SA_[o+7]);                                        \
      u32 x0 = __shfl_xor(h ? w0 : w2, 32, 64);                                \
      u32 x1 = __shfl_xor(h ? w1 : w3, 32, 64);                                \
      union { u32 u[4]; short8 s; } cv;                                        \
      cv.u[0] = h ? x0 : w0;                                                   \
      cv.u[1] = h ? x1 : w1;                                                   \
      cv.u[2] = h ? w2 : x0;                                                   \
      cv.u[3] = h ? w3 : x1;                                                   \
      PF_[kf] = cv.s;                                                          \
    }                                                                          \
  } while (0)

  for (int t = 0; t < NT; ++t){
    const int buf = t & 1;
    __syncthreads();                    // fenced: drains vmcnt+lgkm, barrier
    if (t + 1 < NT) STAGE(t + 1, buf ^ 1);

    const char* base = Buf[buf];

    // ---- sa init = mask bias (same kv rows -> same bias for A and B) ----
    f32x16 saA, saB;
#pragma unroll
    for (int rb = 0; rb < 4; ++rb){
      float4 bv = *(const float4*)&Bb[buf][rb*8 + h*4];
      saA[rb*4+0] = bv.x; saA[rb*4+1] = bv.y; saA[rb*4+2] = bv.z; saA[rb*4+3] = bv.w;
      saB[rb*4+0] = bv.x; saB[rb*4+1] = bv.y; saB[rb*4+2] = bv.z; saB[rb*4+3] = bv.w;
    }

    // ---- QK^T: each K fragment read feeds BOTH groups ----
    __builtin_amdgcn_s_setprio(1);
#pragma unroll
    for (int df = 0; df < 8; ++df){
      short8 kf = *(const short8*)(base + ((df*2 + h) << 9) + (r31 << 4));
      saA = __builtin_amdgcn_mfma_f32_32x32x16_f16(kf, qsA[df], saA, 0, 0, 0);
      saB = __builtin_amdgcn_mfma_f32_32x32x16_f16(kf, qsB[df], saB, 0, 0, 0);
    }
    __builtin_amdgcn_s_setprio(0);

    // ---- softmax + pack, both groups ----
    short8 pfA[2], pfB[2];
    SOFT(saA, mrA, lrA, accA, pfA);
    SOFT(saB, mrB, lrB, accB, pfB);

    // ---- PV: each V fragment read feeds BOTH groups ----
    __builtin_amdgcn_s_setprio(1);
#pragma unroll
    for (int dn = 0; dn < 4; ++dn){
      const int co = (dn*32 + r31) << 4;
      short8 v0 = *(const short8*)(base + 8192 + (h << 11)       + co);
      short8 v1 = *(const short8*)(base + 8192 + ((2 + h) << 11) + co);
      accA[dn] = __builtin_amdgcn_mfma_f32_32x32x16_f16(v0, pfA[0], accA[dn], 0, 0, 0);
      accA[dn] = __builtin_amdgcn_mfma_f32_32x32x16_f16(v1, pfA[1], accA[dn], 0, 0, 0);
      accB[dn] = __builtin_amdgcn_mfma_f32_32x32x16_f16(v0, pfB[0], accB[dn], 0, 0, 0);
      accB[dn] = __builtin_amdgcn_mfma_f32_32x32x16_f16(v1, pfB[1], accB[dn], 0, 0, 0);
    }
    __builtin_amdgcn_s_setprio(0);
  }
#undef SOFT

  // ---- epilogue: both groups ----
  const float invA = 1.0f / lrA, invB = 1.0f / lrB;
  float* OrA = Oh + (size_t)qA * D_;
  float* OrB = Oh + (size_t)(qA + 32) * D_;
#pragma unroll
  for (int dn = 0; dn < 4; ++dn){
#pragma unroll
    for (int rb = 0; rb < 4; ++rb){
      float4 oa, ob;
      oa.x = accA[dn][rb*4+0]*invA; oa.y = accA[dn][rb*4+1]*invA;
      oa.z = accA[dn][rb*4+2]*invA; oa.w = accA[dn][rb*4+3]*invA;
      ob.x = accB[dn][rb*4+0]*invB; ob.y = accB[dn][rb*4+1]*invB;
      ob.z = accB[dn][rb*4+2]*invB; ob.w = accB[dn][rb*4+3]*invB;
      *(float4*)&OrA[dn*32 + rb*8 + h*4] = oa;
      *(float4*)&OrB[dn*32 + rb*8 + h*4] = ob;
    }
  }
}

// ============================ FALLBACK (if ws too small) ============================
DEVI void sync_lds(){
  asm volatile("s_waitcnt lgkmcnt(0)" ::: "memory");
  __builtin_amdgcn_s_barrier();
}
#define TR_READ(dst, addr, IMM) \
  asm volatile("ds_read_b64_tr_b16 %0, %1 offset:" IMM : "=v"(dst) : "v"(addr))

__global__ __launch_bounds__(256, 2)
void sdpa_fallback(const float* __restrict__ Qg, const float* __restrict__ Kg,
                   const float* __restrict__ Vg, const int* __restrict__ Mg,
                   float* __restrict__ Og)
{
  constexpr int S = 2048, D = 128;
  __shared__ __align__(16) short Klds[64*136];
  __shared__ __align__(16) short Vlds[64*128];
  __shared__ __align__(16) float Mlds[64];

  const int tid  = threadIdx.x;
  const int lane = tid & 63;
  const int wv   = tid >> 6;
  const int h    = lane >> 5;
  const int r31  = lane & 31;
  const int r15  = lane & 15;
  const int b4   = (lane >> 4) & 1;
  const int srow = tid >> 5;
  const int scol = tid & 31;

  const int bh = blockIdx.x >> 4;
  const int qb = blockIdx.x & 15;

  const float* Qh = Qg + (size_t)bh * S * D;
  const float* Kh = Kg + (size_t)bh * S * D;
  const float* Vh = Vg + (size_t)bh * S * D;
  const int*   Mh = Mg + (size_t)bh * S;
  float*       Oh = Og + (size_t)bh * S * D;

  const int q0 = qb*128 + wv*32 + r31;

  short8 qs[8];
#pragma unroll
  for (int df = 0; df < 8; ++df){
    const float* p0 = Qh + (size_t)q0 * D + df*16 + h*8;
    float4 a = *(const float4*)(p0);
    float4 b = *(const float4*)(p0 + 4);
    union { u32 u[4]; short8 s; } cv;
    cv.u[0] = pkh(a.x, a.y); cv.u[1] = pkh(a.z, a.w);
    cv.u[2] = pkh(b.x, b.y); cv.u[3] = pkh(b.z, b.w);
    qs[df] = cv.s;
  }

  float4 kr[8], vr[8];
  int mpre = 1;
#pragma unroll
  for (int p = 0; p < 8; ++p){
    int row = p*8 + srow;
    kr[p] = *(const float4*)&Kh[(size_t)row * D + scol*4];
    vr[p] = *(const float4*)&Vh[(size_t)row * D + scol*4];
  }
  if (tid < 64) mpre = Mh[tid];

  f32x16 accO[4];
#pragma unroll
  for (int dn = 0; dn < 4; ++dn) accO[dn] = zero16();
  float mrun = -INFINITY, lrun = 0.0f;

  const u32 vbase = (u32)(size_t)(&Vlds[0]) + (u32)(h*2048 + b4*128 + r15*8);

  for (int t = 0; t < 32; ++t){
#pragma unroll
    for (int p = 0; p < 8; ++p){
      int row = p*8 + srow;
      u32 k0 = pkh(kr[p].x, kr[p].y), k1 = pkh(kr[p].z, kr[p].w);
      *(u64*)&Klds[row*136 + scol*4] = ((u64)k1 << 32) | k0;
      u32 v0 = pkh(vr[p].x, vr[p].y), v1 = pkh(vr[p].z, vr[p].w);
      int E = (row >> 2)*512 + (scol >> 2)*64 + (row & 3)*16 + (scol & 3)*4;
      *(u64*)&Vlds[E] = ((u64)v1 << 32) | v0;
    }
    if (tid < 64) Mlds[tid] = (mpre != 0) ? 1.0f : 0.0f;

    if (t < 31){
      const int kv0 = (t+1)*64;
#pragma unroll
      for (int p = 0; p < 8; ++p){
        int row = kv0 + p*8 + srow;
        kr[p] = *(const float4*)&Kh[(size_t)row * D + scol*4];
        vr[p] = *(const float4*)&Vh[(size_t)row * D + scol*4];
      }
      if (tid < 64) mpre = Mh[kv0 + tid];
    }

    sync_lds();

    f32x16 sa[2];
    sa[0] = zero16(); sa[1] = zero16();
#pragma unroll
    for (int mf = 0; mf < 2; ++mf){
#pragma unroll
      for (int df = 0; df < 8; ++df){
        short8 kf8 = *(const short8*)&Klds[(mf*32 + r31)*136 + df*16 + h*8];
        sa[mf] = __builtin_amdgcn_mfma_f32_32x32x16_f16(kf8, qs[df], sa[mf], 0, 0, 0);
      }
    }

    float pmax = -3.0e38f;
#pragma unroll
    for (int mf = 0; mf < 2; ++mf)
#pragma unroll
      for (int i = 0; i < 16; ++i) pmax = fmaxf(pmax, sa[mf][i]);
    pmax = fmaxf(pmax, __shfl_xor(pmax, 32, 64));
    const float mnew  = fmaxf(mrun, pmax);
    const float scale = __expf(mrun - mnew);
    float psum = 0.0f;
#pragma unroll
    for (int mf = 0; mf < 2; ++mf){
#pragma unroll
      for (int rb = 0; rb < 4; ++rb){
        float4 mv = *(const float4*)&Mlds[mf*32 + rb*8 + h*4];
        float mva[4] = {mv.x, mv.y, mv.z, mv.w};
#pragma unroll
        for (int i = 0; i < 4; ++i){
          float e = __expf(sa[mf][rb*4 + i] - mnew) * mva[i];
          sa[mf][rb*4 + i] = e;
          psum += e;
        }
      }
    }
    psum += __shfl_xor(psum, 32, 64);
    lrun = lrun * scale + psum;
    mrun = mnew;
#pragma unroll
    for (int dn = 0; dn < 4; ++dn)
#pragma unroll
      for (int i = 0; i < 16; ++i) accO[dn][i] *= scale;

    short8 pf8[4];
#pragma unroll
    for (int kf = 0; kf < 4; ++kf){
      const int mf = kf >> 1, o = (kf & 1)*8;
      u32 w0 = pkh(sa[mf][o+0], sa[mf][o+1]);
      u32 w1 = pkh(sa[mf][o+2], sa[mf][o+3]);
      u32 w2 = pkh(sa[mf][o+4], sa[mf][o+5]);
      u32 w3 = pkh(sa[mf][o+6], sa[mf][o+7]);
      u32 s0 = __shfl_xor(w0, 32, 64);
      u32 s1 = __shfl_xor(w1, 32, 64);
      u32 s2 = __shfl_xor(w2, 32, 64);
      u32 s3 = __shfl_xor(w3, 32, 64);
      union { u32 u[4]; short8 s; } cv;
      cv.u[0] = h ? s2 : w0;
      cv.u[1] = h ? s3 : w1;
      cv.u[2] = h ? w2 : s0;
      cv.u[3] = h ? w3 : s1;
      pf8[kf] = cv.s;
    }

#pragma unroll
    for (int dn = 0; dn < 4; ++dn){
      u32 vdn = vbase + dn*256;
      u64 ta0, ta1, tb0, tb1, tc0, tc1, td0, td1;
      TR_READ(ta0, vdn, "0");     TR_READ(ta1, vdn, "1024");
      TR_READ(tb0, vdn, "4096");  TR_READ(tb1, vdn, "5120");
      TR_READ(tc0, vdn, "8192");  TR_READ(tc1, vdn, "9216");
      TR_READ(td0, vdn, "12288"); TR_READ(td1, vdn, "13312");
      asm volatile("s_waitcnt lgkmcnt(0)" ::: "memory");
      __builtin_amdgcn_sched_barrier(0);
      union { u64 q[2]; short8 s; } fa, fb, fc, fd;
      fa.q[0] = ta0; fa.q[1] = ta1;
      fb.q[0] = tb0; fb.q[1] = tb1;
      fc.q[0] = tc0; fc.q[1] = tc1;
      fd.q[0] = td0; fd.q[1] = td1;
      accO[dn] = __builtin_amdgcn_mfma_f32_32x32x16_f16(fa.s, pf8[0], accO[dn], 0,0,0);
      accO[dn] = __builtin_amdgcn_mfma_f32_32x32x16_f16(fb.s, pf8[1], accO[dn], 0,0,0);
      accO[dn] = __builtin_amdgcn_mfma_f32_32x32x16_f16(fc.s, pf8[2], accO[dn], 0,0,0);
      accO[dn] = __builtin_amdgcn_mfma_f32_32x32x16_f16(fd.s, pf8[3], accO[dn], 0,0,0);
    }

    sync_lds();
  }

  const float inv = 1.0f / lrun;
  float* Orow = Oh + (size_t)q0 * D;
#pragma unroll
  for (int dn = 0; dn < 4; ++dn){
#pragma unroll
    for (int rb = 0; rb < 4; ++rb){
      float4 o4;
      o4.x = accO[dn][rb*4+0]*inv;
      o4.y = accO[dn][rb*4+1]*inv;
      o4.z = accO[dn][rb*4+2]*inv;
      o4.w = accO[dn][rb*4+3]*inv;
      *(float4*)&Orow[dn*32 + rb*8 + h*4] = o4;
    }
  }
}

extern "C" void kernel_launch(void* const* d_in, const int* in_sizes, int n_in,
                              void* d_out, int out_size, void* d_ws, size_t ws_size,
                              hipStream_t stream) {
  const float* q = (const float*)d_in[0];
  const float* k = (const float*)d_in[1];
  const float* v = (const float*)d_in[2];
  const int*   m = (const int*)d_in[3];
  float* out = (float*)d_out;
  if (ws_size >= WS_NEED){
    sdpa_prepass<<<dim3(BH_ * NT), dim3(256), 0, stream>>>(k, v, m, (char*)d_ws);
    sdpa_main<<<dim3(512), dim3(256), 0, stream>>>(q, (const char*)d_ws, out);
  } else {
    sdpa_fallback<<<dim3(1024), dim3(256), 0, stream>>>(q, k, v, m, out);
  }
}

// Round 15
// 207.766 us; speedup vs baseline: 1.1465x; 1.0514x over previous
//
#include <hip/hip_runtime.h>
#include <hip/hip_fp16.h>
#include <stdint.h>

typedef __attribute__((ext_vector_type(8))) short short8;
typedef __attribute__((ext_vector_type(16))) float f32x16;
typedef unsigned int u32;
typedef unsigned long long u64;

#define DEVI __device__ __forceinline__

constexpr int S_ = 2048, D_ = 128, BH_ = 64;
constexpr int KVB = 32, NT = S_ / KVB;                    // 64 kv tiles
constexpr size_t IMG_T   = 16384;                         // per (bh,tile): K 8KB + VT 8KB
constexpr size_t IMG_ALL = (size_t)BH_ * NT * IMG_T;      // 64 MB
constexpr size_t MOFF    = IMG_ALL;                       // row-order f32 BIAS (0 / -30000)
constexpr size_t WS_NEED = MOFF + (size_t)BH_ * S_ * 4 + 1024;

// pack two f32 -> two f16 in one u32 (lo=a, hi=b)
DEVI u32 pkh(float a, float b){
  u32 la = (u32)__half_as_ushort(__float2half(a));
  u32 lb = (u32)__half_as_ushort(__float2half(b));
  return la | (lb << 16);
}

DEVI f32x16 zero16(){
  f32x16 z;
#pragma unroll
  for (int i = 0; i < 16; ++i) z[i] = 0.0f;
  return z;
}

// native exp2: v_exp_f32 computes 2^x (single trans-pipe instruction)
DEVI float ex2(float x){
  float r;
  asm("v_exp_f32 %0, %1" : "=v"(r) : "v"(x));
  return r;
}
// 3-input max, single VOP3
DEVI float mx3(float a, float b, float c){
  float r;
  asm("v_max3_f32 %0, %1, %2, %3" : "=v"(r) : "v"(a), "v"(b), "v"(c));
  return r;
}

#define GLOAD16(gsrc, ldst) \
  __builtin_amdgcn_global_load_lds((const __attribute__((address_space(1))) u32*)(gsrc), \
                                   (__attribute__((address_space(3))) u32*)(ldst), 16, 0, 0)
#define GLOAD4(gsrc, ldst) \
  __builtin_amdgcn_global_load_lds((const __attribute__((address_space(1))) u32*)(gsrc), \
                                   (__attribute__((address_space(3))) u32*)(ldst), 4, 0, 0)

// ============================ PRE-PASS ============================
// Per (bh, 32-row tile): K fragment image [k8=0..15][row=0..31] 16B chunks
// (chunk = f16 K[row][k8*8..+8]); VT image [v8=0..3][d=0..127] 16B chunks
// (chunk = f16 V[kv0+v8*8+j][d], j=0..7). Plus row-order f32 BIAS values
// (0 unmasked / -30000 masked) used as the QK MFMA C-initializer.
__global__ __launch_bounds__(256)
void sdpa_prepass(const float* __restrict__ Kg, const float* __restrict__ Vg,
                  const int* __restrict__ Mg, char* __restrict__ ws)
{
  __shared__ float T[32][133];
  const int tid = threadIdx.x;
  const int bh = blockIdx.x >> 6, t = blockIdx.x & 63;
  const int kv0 = t * KVB;
  char* img = ws + (size_t)(bh * NT + t) * IMG_T;
  const int r  = tid >> 3;        // 0..31 kv row
  const int c8 = tid & 7;         // 16-float column chunk

  { // K: direct convert
    const float* src = Kg + ((size_t)bh * S_ + kv0 + r) * D_ + c8 * 16;
    float4 a = ((const float4*)src)[0];
    float4 b = ((const float4*)src)[1];
    float4 c = ((const float4*)src)[2];
    float4 d = ((const float4*)src)[3];
    uint4 o0, o1;
    o0.x = pkh(a.x,a.y); o0.y = pkh(a.z,a.w); o0.z = pkh(b.x,b.y); o0.w = pkh(b.z,b.w);
    o1.x = pkh(c.x,c.y); o1.y = pkh(c.z,c.w); o1.z = pkh(d.x,d.y); o1.w = pkh(d.z,d.w);
    *(uint4*)(img + (c8*2 + 0)*512 + r*16) = o0;
    *(uint4*)(img + (c8*2 + 1)*512 + r*16) = o1;
  }

  { // V: LDS transpose
    const float* src = Vg + ((size_t)bh * S_ + kv0 + r) * D_ + c8 * 16;
    float4 a = ((const float4*)src)[0];
    float4 b = ((const float4*)src)[1];
    float4 c = ((const float4*)src)[2];
    float4 d = ((const float4*)src)[3];
    float x[16] = {a.x,a.y,a.z,a.w,b.x,b.y,b.z,b.w,c.x,c.y,c.z,c.w,d.x,d.y,d.z,d.w};
#pragma unroll
    for (int i = 0; i < 16; ++i) T[r][c8*16 + i] = x[i];
  }
  __syncthreads();
#pragma unroll
  for (int cc = 0; cc < 2; ++cc){
    int ch = cc*256 + tid;              // 0..511
    int v8 = ch >> 7, d = ch & 127;
    float y[8];
#pragma unroll
    for (int j = 0; j < 8; ++j) y[j] = T[v8*8 + j][d];
    uint4 o;
    o.x = pkh(y[0],y[1]); o.y = pkh(y[2],y[3]); o.z = pkh(y[4],y[5]); o.w = pkh(y[6],y[7]);
    *(uint4*)(img + 8192 + ch*16) = o;
  }

  if (t == 0){ // row-order bias values
    float* Mf = (float*)(ws + MOFF) + (size_t)bh * S_;
    for (int i = tid; i < S_; i += 256)
      Mf[i] = (Mg[(size_t)bh * S_ + i] != 0) ? 0.0f : -30000.0f;
  }
}

// ============================ MAIN ============================
// grid 512 (bh-clustered per XCD), 256 thr = 4 waves x 64 q rows (two 32-col
// groups A/B sharing every K/V fragment read). KVB=32, RING-4 LDS (66 KB),
// ONE __syncthreads per TWO tiles (stage t+2,t+3 | compute t,t+1).
// Ring-4 is race-free: stage target (t+2)&3 was last read two iterations ago,
// strictly before the previous barrier. Bias-C-init; native v_exp_f32.
__global__ __launch_bounds__(256, 2)
void sdpa_main(const float* __restrict__ Qg, const char* __restrict__ ws,
               float* __restrict__ Og)
{
  __shared__ __align__(16) char Buf[4][16384];
  __shared__ __align__(16) float Bb[4][64];

  const int tid  = threadIdx.x;
  const int lane = tid & 63;
  const int wv   = tid >> 6;          // 0..3
  const int h    = lane >> 5;
  const int r31  = lane & 31;

  // same-bh blocks clustered per XCD: 512 = 8 xcd x (8 qb x 8 bhl)
  const int bi  = blockIdx.x;
  const int xcd = bi & 7, rr2 = bi >> 3;
  const int qb  = rr2 & 7, bhl = rr2 >> 3;
  const int bh  = xcd*8 + bhl;

  const char*  img0 = ws + (size_t)bh * NT * IMG_T;
  const float* Mf   = (const float*)(ws + MOFF) + (size_t)bh * S_;
  const float* Qh   = Qg + (size_t)bh * S_ * D_;
  float*       Oh   = Og + (size_t)bh * S_ * D_;

  const int qA = qb*256 + wv*64 + r31;   // group A row; group B = qA + 32

  auto STAGE = [&](int tt, int bufi){    // stage one 16 KB image + bias
    const char* g = img0 + (size_t)tt * IMG_T;
#pragma unroll
    for (int j = 0; j < 4; ++j){
      int ch = wv*4 + j;
      GLOAD16(g + ch*1024 + lane*16, &Buf[bufi][ch*1024]);
    }
    GLOAD4(Mf + tt*32 + lane, &Bb[bufi][0]);   // 32 valid + 32 slack
  };

  // ---- Q loads first (first __syncthreads drains them too) ----
  float4 qaA[8], qbA[8], qaB[8], qbB[8];
#pragma unroll
  for (int df = 0; df < 8; ++df){
    const float* pA = Qh + (size_t)qA * D_ + df*16 + h*8;
    const float* pB = Qh + (size_t)(qA + 32) * D_ + df*16 + h*8;
    qaA[df] = *(const float4*)(pA);  qbA[df] = *(const float4*)(pA + 4);
    qaB[df] = *(const float4*)(pB);  qbB[df] = *(const float4*)(pB + 4);
  }
  STAGE(0, 0);
  STAGE(1, 1);

  // f16 B-operand, log2(e) folded (softmax in exp2 domain)
  constexpr float L2E = 1.44269504088896f;
  short8 qsA[8], qsB[8];
#pragma unroll
  for (int df = 0; df < 8; ++df){
    union { u32 u[4]; short8 s; } ca, cb;
    ca.u[0] = pkh(qaA[df].x*L2E, qaA[df].y*L2E);
    ca.u[1] = pkh(qaA[df].z*L2E, qaA[df].w*L2E);
    ca.u[2] = pkh(qbA[df].x*L2E, qbA[df].y*L2E);
    ca.u[3] = pkh(qbA[df].z*L2E, qbA[df].w*L2E);
    cb.u[0] = pkh(qaB[df].x*L2E, qaB[df].y*L2E);
    cb.u[1] = pkh(qaB[df].z*L2E, qaB[df].w*L2E);
    cb.u[2] = pkh(qbB[df].x*L2E, qbB[df].y*L2E);
    cb.u[3] = pkh(qbB[df].z*L2E, qbB[df].w*L2E);
    qsA[df] = ca.s; qsB[df] = cb.s;
  }

  f32x16 accA[4], accB[4];
#pragma unroll
  for (int dn = 0; dn < 4; ++dn){ accA[dn] = zero16(); accB[dn] = zero16(); }
  float mrA = -INFINITY, lrA = 0.0f, mrB = -INFINITY, lrB = 0.0f;

  // softmax + P-pack for one group (bias pre-added via C-init; exp2 domain)
#define SOFT(SA_, MR_, LR_, ACC_, PF_) do {                                    \
    float t0 = mx3(SA_[0], SA_[1], SA_[2]);                                    \
    float t1 = mx3(SA_[3], SA_[4], SA_[5]);                                    \
    float t2 = mx3(SA_[6], SA_[7], SA_[8]);                                    \
    float t3 = mx3(SA_[9], SA_[10], SA_[11]);                                  \
    float t4 = mx3(SA_[12], SA_[13], SA_[14]);                                 \
    float pmax = fmaxf(mx3(t0, t1, t2), mx3(t3, t4, SA_[15]));                 \
    pmax = fmaxf(pmax, __shfl_xor(pmax, 32, 64));                              \
    if (!__all(pmax - MR_ <= 12.0f)){                                          \
      float mnew = fmaxf(MR_, pmax);                                           \
      float sc = ex2(MR_ - mnew);                                              \
      LR_ *= sc;                                                               \
      _Pragma("unroll")                                                        \
      for (int dn = 0; dn < 4; ++dn)                                           \
        _Pragma("unroll")                                                      \
        for (int i = 0; i < 16; ++i) ACC_[dn][i] *= sc;                        \
      MR_ = mnew;                                                              \
    }                                                                          \
    float ps0 = 0.f, ps1 = 0.f, ps2 = 0.f, ps3 = 0.f;                          \
    _Pragma("unroll")                                                          \
    for (int rb = 0; rb < 4; ++rb){                                            \
      float e0 = ex2(SA_[rb*4+0] - MR_);                                       \
      float e1 = ex2(SA_[rb*4+1] - MR_);                                       \
      float e2 = ex2(SA_[rb*4+2] - MR_);                                       \
      float e3 = ex2(SA_[rb*4+3] - MR_);                                       \
      SA_[rb*4+0]=e0; SA_[rb*4+1]=e1; SA_[rb*4+2]=e2; SA_[rb*4+3]=e3;          \
      ps0 += e0; ps1 += e1; ps2 += e2; ps3 += e3;                              \
    }                                                                          \
    float psum = (ps0 + ps1) + (ps2 + ps3);                                    \
    psum += __shfl_xor(psum, 32, 64);                                          \
    LR_ += psum;                                                               \
    _Pragma("unroll")                                                          \
    for (int kf = 0; kf < 2; ++kf){                                            \
      const int o = kf*8;                                                      \
      u32 w0 = pkh(SA_[o+0], SA_[o+1]);                                        \
      u32 w1 = pkh(SA_[o+2], SA_[o+3]);                                        \
      u32 w2 = pkh(SA_[o+4], SA_[o+5]);                                        \
      u32 w3 = pkh(SA_[o+6], SA_[o+7]);                                        \
      u32 x0 = __shfl_xor(h ? w0 : w2, 32, 64);                                \
      u32 x1 = __shfl_xor(h ? w1 : w3, 32, 64);                                \
      union { u32 u[4]; short8 s; } cv;                                        \
      cv.u[0] = h ? x0 : w0;                                                   \
      cv.u[1] = h ? x1 : w1;                                                   \
      cv.u[2] = h ? w2 : x0;                                                   \
      cv.u[3] = h ? w3 : x1;                                                   \
      PF_[kf] = cv.s;                                                          \
    }                                                                          \
  } while (0)

  // full tile: bias-init -> QK -> softmax(A,B) -> PV, all reading ring slot BUF_
#define TILE(BUF_) do {                                                        \
    const char* base = Buf[BUF_];                                              \
    f32x16 saA, saB;                                                           \
    _Pragma("unroll")                                                          \
    for (int rb = 0; rb < 4; ++rb){                                            \
      float4 bv = *(const float4*)&Bb[BUF_][rb*8 + h*4];                       \
      saA[rb*4+0] = bv.x; saA[rb*4+1] = bv.y;                                  \
      saA[rb*4+2] = bv.z; saA[rb*4+3] = bv.w;                                  \
      saB[rb*4+0] = bv.x; saB[rb*4+1] = bv.y;                                  \
      saB[rb*4+2] = bv.z; saB[rb*4+3] = bv.w;                                  \
    }                                                                          \
    __builtin_amdgcn_s_setprio(1);                                             \
    _Pragma("unroll")                                                          \
    for (int df = 0; df < 8; ++df){                                            \
      short8 kf = *(const short8*)(base + ((df*2 + h) << 9) + (r31 << 4));     \
      saA = __builtin_amdgcn_mfma_f32_32x32x16_f16(kf, qsA[df], saA, 0, 0, 0); \
      saB = __builtin_amdgcn_mfma_f32_32x32x16_f16(kf, qsB[df], saB, 0, 0, 0); \
    }                                                                          \
    __builtin_amdgcn_s_setprio(0);                                             \
    short8 pfA[2], pfB[2];                                                     \
    SOFT(saA, mrA, lrA, accA, pfA);                                            \
    SOFT(saB, mrB, lrB, accB, pfB);                                            \
    __builtin_amdgcn_s_setprio(1);                                             \
    _Pragma("unroll")                                                          \
    for (int dn = 0; dn < 4; ++dn){                                            \
      const int co = (dn*32 + r31) << 4;                                       \
      short8 v0 = *(const short8*)(base + 8192 + (h << 11)       + co);        \
      short8 v1 = *(const short8*)(base + 8192 + ((2 + h) << 11) + co);        \
      accA[dn] = __builtin_amdgcn_mfma_f32_32x32x16_f16(v0, pfA[0], accA[dn], 0, 0, 0); \
      accA[dn] = __builtin_amdgcn_mfma_f32_32x32x16_f16(v1, pfA[1], accA[dn], 0, 0, 0); \
      accB[dn] = __builtin_amdgcn_mfma_f32_32x32x16_f16(v0, pfB[0], accB[dn], 0, 0, 0); \
      accB[dn] = __builtin_amdgcn_mfma_f32_32x32x16_f16(v1, pfB[1], accB[dn], 0, 0, 0); \
    }                                                                          \
    __builtin_amdgcn_s_setprio(0);                                             \
  } while (0)

  for (int t = 0; t < NT; t += 2){
    __syncthreads();                    // fenced: drains vmcnt+lgkm, barrier
    if (t + 2 < NT) STAGE(t + 2, (t + 2) & 3);
    if (t + 3 < NT) STAGE(t + 3, (t + 3) & 3);
    TILE(t & 3);
    TILE((t + 1) & 3);
  }
#undef TILE
#undef SOFT

  // ---- epilogue: both groups ----
  const float invA = 1.0f / lrA, invB = 1.0f / lrB;
  float* OrA = Oh + (size_t)qA * D_;
  float* OrB = Oh + (size_t)(qA + 32) * D_;
#pragma unroll
  for (int dn = 0; dn < 4; ++dn){
#pragma unroll
    for (int rb = 0; rb < 4; ++rb){
      float4 oa, ob;
      oa.x = accA[dn][rb*4+0]*invA; oa.y = accA[dn][rb*4+1]*invA;
      oa.z = accA[dn][rb*4+2]*invA; oa.w = accA[dn][rb*4+3]*invA;
      ob.x = accB[dn][rb*4+0]*invB; ob.y = accB[dn][rb*4+1]*invB;
      ob.z = accB[dn][rb*4+2]*invB; ob.w = accB[dn][rb*4+3]*invB;
      *(float4*)&OrA[dn*32 + rb*8 + h*4] = oa;
      *(float4*)&OrB[dn*32 + rb*8 + h*4] = ob;
    }
  }
}

// ============================ FALLBACK (if ws too small) ============================
DEVI void sync_lds(){
  asm volatile("s_waitcnt lgkmcnt(0)" ::: "memory");
  __builtin_amdgcn_s_barrier();
}
#define TR_READ(dst, addr, IMM) \
  asm volatile("ds_read_b64_tr_b16 %0, %1 offset:" IMM : "=v"(dst) : "v"(addr))

__global__ __launch_bounds__(256, 2)
void sdpa_fallback(const float* __restrict__ Qg, const float* __restrict__ Kg,
                   const float* __restrict__ Vg, const int* __restrict__ Mg,
                   float* __restrict__ Og)
{
  constexpr int S = 2048, D = 128;
  __shared__ __align__(16) short Klds[64*136];
  __shared__ __align__(16) short Vlds[64*128];
  __shared__ __align__(16) float Mlds[64];

  const int tid  = threadIdx.x;
  const int lane = tid & 63;
  const int wv   = tid >> 6;
  const int h    = lane >> 5;
  const int r31  = lane & 31;
  const int r15  = lane & 15;
  const int b4   = (lane >> 4) & 1;
  const int srow = tid >> 5;
  const int scol = tid & 31;

  const int bh = blockIdx.x >> 4;
  const int qb = blockIdx.x & 15;

  const float* Qh = Qg + (size_t)bh * S * D;
  const float* Kh = Kg + (size_t)bh * S * D;
  const float* Vh = Vg + (size_t)bh * S * D;
  const int*   Mh = Mg + (size_t)bh * S;
  float*       Oh = Og + (size_t)bh * S * D;

  const int q0 = qb*128 + wv*32 + r31;

  short8 qs[8];
#pragma unroll
  for (int df = 0; df < 8; ++df){
    const float* p0 = Qh + (size_t)q0 * D + df*16 + h*8;
    float4 a = *(const float4*)(p0);
    float4 b = *(const float4*)(p0 + 4);
    union { u32 u[4]; short8 s; } cv;
    cv.u[0] = pkh(a.x, a.y); cv.u[1] = pkh(a.z, a.w);
    cv.u[2] = pkh(b.x, b.y); cv.u[3] = pkh(b.z, b.w);
    qs[df] = cv.s;
  }

  float4 kr[8], vr[8];
  int mpre = 1;
#pragma unroll
  for (int p = 0; p < 8; ++p){
    int row = p*8 + srow;
    kr[p] = *(const float4*)&Kh[(size_t)row * D + scol*4];
    vr[p] = *(const float4*)&Vh[(size_t)row * D + scol*4];
  }
  if (tid < 64) mpre = Mh[tid];

  f32x16 accO[4];
#pragma unroll
  for (int dn = 0; dn < 4; ++dn) accO[dn] = zero16();
  float mrun = -INFINITY, lrun = 0.0f;

  const u32 vbase = (u32)(size_t)(&Vlds[0]) + (u32)(h*2048 + b4*128 + r15*8);

  for (int t = 0; t < 32; ++t){
#pragma unroll
    for (int p = 0; p < 8; ++p){
      int row = p*8 + srow;
      u32 k0 = pkh(kr[p].x, kr[p].y), k1 = pkh(kr[p].z, kr[p].w);
      *(u64*)&Klds[row*136 + scol*4] = ((u64)k1 << 32) | k0;
      u32 v0 = pkh(vr[p].x, vr[p].y), v1 = pkh(vr[p].z, vr[p].w);
      int E = (row >> 2)*512 + (scol >> 2)*64 + (row & 3)*16 + (scol & 3)*4;
      *(u64*)&Vlds[E] = ((u64)v1 << 32) | v0;
    }
    if (tid < 64) Mlds[tid] = (mpre != 0) ? 1.0f : 0.0f;

    if (t < 31){
      const int kv0 = (t+1)*64;
#pragma unroll
      for (int p = 0; p < 8; ++p){
        int row = kv0 + p*8 + srow;
        kr[p] = *(const float4*)&Kh[(size_t)row * D + scol*4];
        vr[p] = *(const float4*)&Vh[(size_t)row * D + scol*4];
      }
      if (tid < 64) mpre = Mh[kv0 + tid];
    }

    sync_lds();

    f32x16 sa[2];
    sa[0] = zero16(); sa[1] = zero16();
#pragma unroll
    for (int mf = 0; mf < 2; ++mf){
#pragma unroll
      for (int df = 0; df < 8; ++df){
        short8 kf8 = *(const short8*)&Klds[(mf*32 + r31)*136 + df*16 + h*8];
        sa[mf] = __builtin_amdgcn_mfma_f32_32x32x16_f16(kf8, qs[df], sa[mf], 0, 0, 0);
      }
    }

    float pmax = -3.0e38f;
#pragma unroll
    for (int mf = 0; mf < 2; ++mf)
#pragma unroll
      for (int i = 0; i < 16; ++i) pmax = fmaxf(pmax, sa[mf][i]);
    pmax = fmaxf(pmax, __shfl_xor(pmax, 32, 64));
    const float mnew  = fmaxf(mrun, pmax);
    const float scale = __expf(mrun - mnew);
    float psum = 0.0f;
#pragma unroll
    for (int mf = 0; mf < 2; ++mf){
#pragma unroll
      for (int rb = 0; rb < 4; ++rb){
        float4 mv = *(const float4*)&Mlds[mf*32 + rb*8 + h*4];
        float mva[4] = {mv.x, mv.y, mv.z, mv.w};
#pragma unroll
        for (int i = 0; i < 4; ++i){
          float e = __expf(sa[mf][rb*4 + i] - mnew) * mva[i];
          sa[mf][rb*4 + i] = e;
          psum += e;
        }
      }
    }
    psum += __shfl_xor(psum, 32, 64);
    lrun = lrun * scale + psum;
    mrun = mnew;
#pragma unroll
    for (int dn = 0; dn < 4; ++dn)
#pragma unroll
      for (int i = 0; i < 16; ++i) accO[dn][i] *= scale;

    short8 pf8[4];
#pragma unroll
    for (int kf = 0; kf < 4; ++kf){
      const int mf = kf >> 1, o = (kf & 1)*8;
      u32 w0 = pkh(sa[mf][o+0], sa[mf][o+1]);
      u32 w1 = pkh(sa[mf][o+2], sa[mf][o+3]);
      u32 w2 = pkh(sa[mf][o+4], sa[mf][o+5]);
      u32 w3 = pkh(sa[mf][o+6], sa[mf][o+7]);
      u32 s0 = __shfl_xor(w0, 32, 64);
      u32 s1 = __shfl_xor(w1, 32, 64);
      u32 s2 = __shfl_xor(w2, 32, 64);
      u32 s3 = __shfl_xor(w3, 32, 64);
      union { u32 u[4]; short8 s; } cv;
      cv.u[0] = h ? s2 : w0;
      cv.u[1] = h ? s3 : w1;
      cv.u[2] = h ? w2 : s0;
      cv.u[3] = h ? w3 : s1;
      pf8[kf] = cv.s;
    }

#pragma unroll
    for (int dn = 0; dn < 4; ++dn){
      u32 vdn = vbase + dn*256;
      u64 ta0, ta1, tb0, tb1, tc0, tc1, td0, td1;
      TR_READ(ta0, vdn, "0");     TR_READ(ta1, vdn, "1024");
      TR_READ(tb0, vdn, "4096");  TR_READ(tb1, vdn, "5120");
      TR_READ(tc0, vdn, "8192");  TR_READ(tc1, vdn, "9216");
      TR_READ(td0, vdn, "12288"); TR_READ(td1, vdn, "13312");
      asm volatile("s_waitcnt lgkmcnt(0)" ::: "memory");
      __builtin_amdgcn_sched_barrier(0);
      union { u64 q[2]; short8 s; } fa, fb, fc, fd;
      fa.q[0] = ta0; fa.q[1] = ta1;
      fb.q[0] = tb0; fb.q[1] = tb1;
      fc.q[0] = tc0; fc.q[1] = tc1;
      fd.q[0] = td0; fd.q[1] = td1;
      accO[dn] = __builtin_amdgcn_mfma_f32_32x32x16_f16(fa.s, pf8[0], accO[dn], 0,0,0);
      accO[dn] = __builtin_amdgcn_mfma_f32_32x32x16_f16(fb.s, pf8[1], accO[dn], 0,0,0);
      accO[dn] = __builtin_amdgcn_mfma_f32_32x32x16_f16(fc.s, pf8[2], accO[dn], 0,0,0);
      accO[dn] = __builtin_amdgcn_mfma_f32_32x32x16_f16(fd.s, pf8[3], accO[dn], 0,0,0);
    }

    sync_lds();
  }

  const float inv = 1.0f / lrun;
  float* Orow = Oh + (size_t)q0 * D;
#pragma unroll
  for (int dn = 0; dn < 4; ++dn){
#pragma unroll
    for (int rb = 0; rb < 4; ++rb){
      float4 o4;
      o4.x = accO[dn][rb*4+0]*inv;
      o4.y = accO[dn][rb*4+1]*inv;
      o4.z = accO[dn][rb*4+2]*inv;
      o4.w = accO[dn][rb*4+3]*inv;
      *(float4*)&Orow[dn*32 + rb*8 + h*4] = o4;
    }
  }
}

extern "C" void kernel_launch(void* const* d_in, const int* in_sizes, int n_in,
                              void* d_out, int out_size, void* d_ws, size_t ws_size,
                              hipStream_t stream) {
  const float* q = (const float*)d_in[0];
  const float* k = (const float*)d_in[1];
  const float* v = (const float*)d_in[2];
  const int*   m = (const int*)d_in[3];
  float* out = (float*)d_out;
  if (ws_size >= WS_NEED){
    sdpa_prepass<<<dim3(BH_ * NT), dim3(256), 0, stream>>>(k, v, m, (char*)d_ws);
    sdpa_main<<<dim3(512), dim3(256), 0, stream>>>(q, (const char*)d_ws, out);
  } else {
    sdpa_fallback<<<dim3(1024), dim3(256), 0, stream>>>(q, k, v, m, out);
  }
}

// Round 17
// 197.626 us; speedup vs baseline: 1.2054x; 1.0513x over previous
//
#include <hip/hip_runtime.h>
#include <hip/hip_fp16.h>
#include <stdint.h>

typedef __attribute__((ext_vector_type(8))) short short8;
typedef __attribute__((ext_vector_type(16))) float f32x16;
typedef __attribute__((ext_vector_type(2))) unsigned u32x2;
typedef __attribute__((ext_vector_type(2))) __fp16 h2;
typedef unsigned int u32;
typedef unsigned long long u64;

#define DEVI __device__ __forceinline__

constexpr int S_ = 2048, D_ = 128, BH_ = 64;
constexpr int KVB = 32, NT = S_ / KVB;                    // 64 kv tiles
constexpr size_t IMG_T   = 16384;                         // per (bh,tile): K 8KB + VT 8KB
constexpr size_t IMG_ALL = (size_t)BH_ * NT * IMG_T;      // 64 MB
constexpr size_t MOFF    = IMG_ALL;                       // row-order f32 BIAS (0 / -30000)
constexpr size_t WS_NEED = MOFF + (size_t)BH_ * S_ * 4 + 1024;

// pack two f32 -> two f16 in one u32 via single v_cvt_pkrtz_f16_f32
DEVI u32 pkh(float a, float b){
  h2 r = __builtin_amdgcn_cvt_pkrtz(a, b);
  union { h2 h; u32 u; } c; c.h = r; return c.u;
}

DEVI f32x16 zero16(){
  f32x16 z;
#pragma unroll
  for (int i = 0; i < 16; ++i) z[i] = 0.0f;
  return z;
}

// native exp2: v_exp_f32 computes 2^x (single trans-pipe instruction)
DEVI float ex2(float x){
  float r;
  asm("v_exp_f32 %0, %1" : "=v"(r) : "v"(x));
  return r;
}
// 3-input max, single VOP3
DEVI float mx3(float a, float b, float c){
  float r;
  asm("v_max3_f32 %0, %1, %2, %3" : "=v"(r) : "v"(a), "v"(b), "v"(c));
  return r;
}
// lane<32 <-> lane>=32 exchange: vdst-hi row swaps with vsrc-lo row
DEVI u32x2 plswap(u32 a, u32 b){
  return __builtin_amdgcn_permlane32_swap(a, b, false, false);
}
// cross-half max / sum (replaces __shfl_xor(x,32) + op; off the LDS pipe)
DEVI float xmax32(float x){
  u32x2 r = plswap(__float_as_uint(x), __float_as_uint(x));
  return fmaxf(__uint_as_float(r.x), __uint_as_float(r.y));
}
DEVI float xadd32(float x){
  u32x2 r = plswap(__float_as_uint(x), __float_as_uint(x));
  return __uint_as_float(r.x) + __uint_as_float(r.y);
}

#define GLOAD16(gsrc, ldst) \
  __builtin_amdgcn_global_load_lds((const __attribute__((address_space(1))) u32*)(gsrc), \
                                   (__attribute__((address_space(3))) u32*)(ldst), 16, 0, 0)
#define GLOAD4(gsrc, ldst) \
  __builtin_amdgcn_global_load_lds((const __attribute__((address_space(1))) u32*)(gsrc), \
                                   (__attribute__((address_space(3))) u32*)(ldst), 4, 0, 0)

// ============================ PRE-PASS ============================
// Per (bh, 32-row tile): K fragment image [k8=0..15][row=0..31] 16B chunks
// (chunk = f16 K[row][k8*8..+8]); VT image [v8=0..3][d=0..127] 16B chunks
// (chunk = f16 V[kv0+v8*8+j][d], j=0..7). Plus row-order f32 BIAS values
// (0 unmasked / -30000 masked) used as the QK MFMA C-initializer.
__global__ __launch_bounds__(256)
void sdpa_prepass(const float* __restrict__ Kg, const float* __restrict__ Vg,
                  const int* __restrict__ Mg, char* __restrict__ ws)
{
  __shared__ float T[32][133];
  const int tid = threadIdx.x;
  const int bh = blockIdx.x >> 6, t = blockIdx.x & 63;
  const int kv0 = t * KVB;
  char* img = ws + (size_t)(bh * NT + t) * IMG_T;
  const int r  = tid >> 3;        // 0..31 kv row
  const int c8 = tid & 7;         // 16-float column chunk

  { // K: direct convert
    const float* src = Kg + ((size_t)bh * S_ + kv0 + r) * D_ + c8 * 16;
    float4 a = ((const float4*)src)[0];
    float4 b = ((const float4*)src)[1];
    float4 c = ((const float4*)src)[2];
    float4 d = ((const float4*)src)[3];
    uint4 o0, o1;
    o0.x = pkh(a.x,a.y); o0.y = pkh(a.z,a.w); o0.z = pkh(b.x,b.y); o0.w = pkh(b.z,b.w);
    o1.x = pkh(c.x,c.y); o1.y = pkh(c.z,c.w); o1.z = pkh(d.x,d.y); o1.w = pkh(d.z,d.w);
    *(uint4*)(img + (c8*2 + 0)*512 + r*16) = o0;
    *(uint4*)(img + (c8*2 + 1)*512 + r*16) = o1;
  }

  { // V: LDS transpose
    const float* src = Vg + ((size_t)bh * S_ + kv0 + r) * D_ + c8 * 16;
    float4 a = ((const float4*)src)[0];
    float4 b = ((const float4*)src)[1];
    float4 c = ((const float4*)src)[2];
    float4 d = ((const float4*)src)[3];
    float x[16] = {a.x,a.y,a.z,a.w,b.x,b.y,b.z,b.w,c.x,c.y,c.z,c.w,d.x,d.y,d.z,d.w};
#pragma unroll
    for (int i = 0; i < 16; ++i) T[r][c8*16 + i] = x[i];
  }
  __syncthreads();
#pragma unroll
  for (int cc = 0; cc < 2; ++cc){
    int ch = cc*256 + tid;              // 0..511
    int v8 = ch >> 7, d = ch & 127;
    float y[8];
#pragma unroll
    for (int j = 0; j < 8; ++j) y[j] = T[v8*8 + j][d];
    uint4 o;
    o.x = pkh(y[0],y[1]); o.y = pkh(y[2],y[3]); o.z = pkh(y[4],y[5]); o.w = pkh(y[6],y[7]);
    *(uint4*)(img + 8192 + ch*16) = o;
  }

  if (t == 0){ // row-order bias values
    float* Mf = (float*)(ws + MOFF) + (size_t)bh * S_;
    for (int i = tid; i < S_; i += 256)
      Mf[i] = (Mg[(size_t)bh * S_ + i] != 0) ? 0.0f : -30000.0f;
  }
}

// ============================ MAIN ============================
// grid 512 (bh-clustered per XCD), 256 thr = 4 waves x 64 q rows (two 32-col
// groups A/B sharing every K/V fragment read). KVB=32, RING-4 LDS (66 KB),
// ONE __syncthreads per TWO tiles. permlane32_swap replaces all xor-32
// shuffles (pack: one swap fills two fragment words). Bias-C-init; v_exp_f32.
__global__ __launch_bounds__(256, 2)
void sdpa_main(const float* __restrict__ Qg, const char* __restrict__ ws,
               float* __restrict__ Og)
{
  __shared__ __align__(16) char Buf[4][16384];
  __shared__ __align__(16) float Bb[4][64];

  const int tid  = threadIdx.x;
  const int lane = tid & 63;
  const int wv   = tid >> 6;          // 0..3
  const int h    = lane >> 5;
  const int r31  = lane & 31;

  // same-bh blocks clustered per XCD: 512 = 8 xcd x (8 qb x 8 bhl)
  const int bi  = blockIdx.x;
  const int xcd = bi & 7, rr2 = bi >> 3;
  const int qb  = rr2 & 7, bhl = rr2 >> 3;
  const int bh  = xcd*8 + bhl;

  const char*  img0 = ws + (size_t)bh * NT * IMG_T;
  const float* Mf   = (const float*)(ws + MOFF) + (size_t)bh * S_;
  const float* Qh   = Qg + (size_t)bh * S_ * D_;
  float*       Oh   = Og + (size_t)bh * S_ * D_;

  const int qA = qb*256 + wv*64 + r31;   // group A row; group B = qA + 32

  auto STAGE = [&](int tt, int bufi){    // stage one 16 KB image + bias
    const char* g = img0 + (size_t)tt * IMG_T;
#pragma unroll
    for (int j = 0; j < 4; ++j){
      int ch = wv*4 + j;
      GLOAD16(g + ch*1024 + lane*16, &Buf[bufi][ch*1024]);
    }
    GLOAD4(Mf + tt*32 + lane, &Bb[bufi][0]);   // 32 valid + 32 slack
  };

  // ---- Q loads first (first __syncthreads drains them too) ----
  float4 qaA[8], qbA[8], qaB[8], qbB[8];
#pragma unroll
  for (int df = 0; df < 8; ++df){
    const float* pA = Qh + (size_t)qA * D_ + df*16 + h*8;
    const float* pB = Qh + (size_t)(qA + 32) * D_ + df*16 + h*8;
    qaA[df] = *(const float4*)(pA);  qbA[df] = *(const float4*)(pA + 4);
    qaB[df] = *(const float4*)(pB);  qbB[df] = *(const float4*)(pB + 4);
  }
  STAGE(0, 0);
  STAGE(1, 1);

  // f16 B-operand, log2(e) folded (softmax in exp2 domain)
  constexpr float L2E = 1.44269504088896f;
  short8 qsA[8], qsB[8];
#pragma unroll
  for (int df = 0; df < 8; ++df){
    union { u32 u[4]; short8 s; } ca, cb;
    ca.u[0] = pkh(qaA[df].x*L2E, qaA[df].y*L2E);
    ca.u[1] = pkh(qaA[df].z*L2E, qaA[df].w*L2E);
    ca.u[2] = pkh(qbA[df].x*L2E, qbA[df].y*L2E);
    ca.u[3] = pkh(qbA[df].z*L2E, qbA[df].w*L2E);
    cb.u[0] = pkh(qaB[df].x*L2E, qaB[df].y*L2E);
    cb.u[1] = pkh(qaB[df].z*L2E, qaB[df].w*L2E);
    cb.u[2] = pkh(qbB[df].x*L2E, qbB[df].y*L2E);
    cb.u[3] = pkh(qbB[df].z*L2E, qbB[df].w*L2E);
    qsA[df] = ca.s; qsB[df] = cb.s;
  }

  f32x16 accA[4], accB[4];
#pragma unroll
  for (int dn = 0; dn < 4; ++dn){ accA[dn] = zero16(); accB[dn] = zero16(); }
  float mrA = -INFINITY, lrA = 0.0f, mrB = -INFINITY, lrB = 0.0f;

  // softmax + P-pack for one group (bias pre-added via C-init; exp2 domain)
#define SOFT(SA_, MR_, LR_, ACC_, PF_) do {                                    \
    float t0 = mx3(SA_[0], SA_[1], SA_[2]);                                    \
    float t1 = mx3(SA_[3], SA_[4], SA_[5]);                                    \
    float t2 = mx3(SA_[6], SA_[7], SA_[8]);                                    \
    float t3 = mx3(SA_[9], SA_[10], SA_[11]);                                  \
    float t4 = mx3(SA_[12], SA_[13], SA_[14]);                                 \
    float pmax = fmaxf(mx3(t0, t1, t2), mx3(t3, t4, SA_[15]));                 \
    pmax = xmax32(pmax);                                                       \
    if (!__all(pmax - MR_ <= 12.0f)){                                          \
      float mnew = fmaxf(MR_, pmax);                                           \
      float sc = ex2(MR_ - mnew);                                              \
      LR_ *= sc;                                                               \
      _Pragma("unroll")                                                        \
      for (int dn = 0; dn < 4; ++dn)                                           \
        _Pragma("unroll")                                                      \
        for (int i = 0; i < 16; ++i) ACC_[dn][i] *= sc;                        \
      MR_ = mnew;                                                              \
    }                                                                          \
    float ps0 = 0.f, ps1 = 0.f, ps2 = 0.f, ps3 = 0.f;                          \
    _Pragma("unroll")                                                          \
    for (int rb = 0; rb < 4; ++rb){                                            \
      float e0 = ex2(SA_[rb*4+0] - MR_);                                       \
      float e1 = ex2(SA_[rb*4+1] - MR_);                                       \
      float e2 = ex2(SA_[rb*4+2] - MR_);                                       \
      float e3 = ex2(SA_[rb*4+3] - MR_);                                       \
      SA_[rb*4+0]=e0; SA_[rb*4+1]=e1; SA_[rb*4+2]=e2; SA_[rb*4+3]=e3;          \
      ps0 += e0; ps1 += e1; ps2 += e2; ps3 += e3;                              \
    }                                                                          \
    float psum = (ps0 + ps1) + (ps2 + ps3);                                    \
    LR_ += xadd32(psum);                                                       \
    _Pragma("unroll")                                                          \
    for (int kf = 0; kf < 2; ++kf){                                            \
      const int o = kf*8;                                                      \
      u32 w0 = pkh(SA_[o+0], SA_[o+1]);                                        \
      u32 w1 = pkh(SA_[o+2], SA_[o+3]);                                        \
      u32 w2 = pkh(SA_[o+4], SA_[o+5]);                                        \
      u32 w3 = pkh(SA_[o+6], SA_[o+7]);                                        \
      u32x2 p0 = plswap(w0, w2);   /* .x = frag word0, .y = frag word2 */      \
      u32x2 p1 = plswap(w1, w3);   /* .x = frag word1, .y = frag word3 */      \
      union { u32 u[4]; short8 s; } cv;                                        \
      cv.u[0] = p0.x;                                                          \
      cv.u[1] = p1.x;                                                          \
      cv.u[2] = p0.y;                                                          \
      cv.u[3] = p1.y;                                                          \
      PF_[kf] = cv.s;                                                          \
    }                                                                          \
  } while (0)

  // full tile: bias-init -> QK -> softmax(A,B) -> PV, all reading ring slot BUF_
#define TILE(BUF_) do {                                                        \
    const char* base = Buf[BUF_];                                              \
    f32x16 saA, saB;                                                           \
    _Pragma("unroll")                                                          \
    for (int rb = 0; rb < 4; ++rb){                                            \
      float4 bv = *(const float4*)&Bb[BUF_][rb*8 + h*4];                       \
      saA[rb*4+0] = bv.x; saA[rb*4+1] = bv.y;                                  \
      saA[rb*4+2] = bv.z; saA[rb*4+3] = bv.w;                                  \
      saB[rb*4+0] = bv.x; saB[rb*4+1] = bv.y;                                  \
      saB[rb*4+2] = bv.z; saB[rb*4+3] = bv.w;                                  \
    }                                                                          \
    __builtin_amdgcn_s_setprio(1);                                             \
    _Pragma("unroll")                                                          \
    for (int df = 0; df < 8; ++df){                                            \
      short8 kf = *(const short8*)(base + ((df*2 + h) << 9) + (r31 << 4));     \
      saA = __builtin_amdgcn_mfma_f32_32x32x16_f16(kf, qsA[df], saA, 0, 0, 0); \
      saB = __builtin_amdgcn_mfma_f32_32x32x16_f16(kf, qsB[df], saB, 0, 0, 0); \
    }                                                                          \
    __builtin_amdgcn_s_setprio(0);                                             \
    short8 pfA[2], pfB[2];                                                     \
    SOFT(saA, mrA, lrA, accA, pfA);                                            \
    SOFT(saB, mrB, lrB, accB, pfB);                                            \
    __builtin_amdgcn_s_setprio(1);                                             \
    _Pragma("unroll")                                                          \
    for (int dn = 0; dn < 4; ++dn){                                            \
      const int co = (dn*32 + r31) << 4;                                       \
      short8 v0 = *(const short8*)(base + 8192 + (h << 11)       + co);        \
      short8 v1 = *(const short8*)(base + 8192 + ((2 + h) << 11) + co);        \
      accA[dn] = __builtin_amdgcn_mfma_f32_32x32x16_f16(v0, pfA[0], accA[dn], 0, 0, 0); \
      accA[dn] = __builtin_amdgcn_mfma_f32_32x32x16_f16(v1, pfA[1], accA[dn], 0, 0, 0); \
      accB[dn] = __builtin_amdgcn_mfma_f32_32x32x16_f16(v0, pfB[0], accB[dn], 0, 0, 0); \
      accB[dn] = __builtin_amdgcn_mfma_f32_32x32x16_f16(v1, pfB[1], accB[dn], 0, 0, 0); \
    }                                                                          \
    __builtin_amdgcn_s_setprio(0);                                             \
  } while (0)

  for (int t = 0; t < NT; t += 2){
    __syncthreads();                    // fenced: drains vmcnt+lgkm, barrier
    if (t + 2 < NT) STAGE(t + 2, (t + 2) & 3);
    if (t + 3 < NT) STAGE(t + 3, (t + 3) & 3);
    TILE(t & 3);
    TILE((t + 1) & 3);
  }
#undef TILE
#undef SOFT

  // ---- epilogue: both groups ----
  const float invA = 1.0f / lrA, invB = 1.0f / lrB;
  float* OrA = Oh + (size_t)qA * D_;
  float* OrB = Oh + (size_t)(qA + 32) * D_;
#pragma unroll
  for (int dn = 0; dn < 4; ++dn){
#pragma unroll
    for (int rb = 0; rb < 4; ++rb){
      float4 oa, ob;
      oa.x = accA[dn][rb*4+0]*invA; oa.y = accA[dn][rb*4+1]*invA;
      oa.z = accA[dn][rb*4+2]*invA; oa.w = accA[dn][rb*4+3]*invA;
      ob.x = accB[dn][rb*4+0]*invB; ob.y = accB[dn][rb*4+1]*invB;
      ob.z = accB[dn][rb*4+2]*invB; ob.w = accB[dn][rb*4+3]*invB;
      *(float4*)&OrA[dn*32 + rb*8 + h*4] = oa;
      *(float4*)&OrB[dn*32 + rb*8 + h*4] = ob;
    }
  }
}

// ============================ FALLBACK (if ws too small) ============================
DEVI void sync_lds(){
  asm volatile("s_waitcnt lgkmcnt(0)" ::: "memory");
  __builtin_amdgcn_s_barrier();
}
#define TR_READ(dst, addr, IMM) \
  asm volatile("ds_read_b64_tr_b16 %0, %1 offset:" IMM : "=v"(dst) : "v"(addr))

__global__ __launch_bounds__(256, 2)
void sdpa_fallback(const float* __restrict__ Qg, const float* __restrict__ Kg,
                   const float* __restrict__ Vg, const int* __restrict__ Mg,
                   float* __restrict__ Og)
{
  constexpr int S = 2048, D = 128;
  __shared__ __align__(16) short Klds[64*136];
  __shared__ __align__(16) short Vlds[64*128];
  __shared__ __align__(16) float Mlds[64];

  const int tid  = threadIdx.x;
  const int lane = tid & 63;
  const int wv   = tid >> 6;
  const int h    = lane >> 5;
  const int r31  = lane & 31;
  const int r15  = lane & 15;
  const int b4   = (lane >> 4) & 1;
  const int srow = tid >> 5;
  const int scol = tid & 31;

  const int bh = blockIdx.x >> 4;
  const int qb = blockIdx.x & 15;

  const float* Qh = Qg + (size_t)bh * S * D;
  const float* Kh = Kg + (size_t)bh * S * D;
  const float* Vh = Vg + (size_t)bh * S * D;
  const int*   Mh = Mg + (size_t)bh * S;
  float*       Oh = Og + (size_t)bh * S * D;

  const int q0 = qb*128 + wv*32 + r31;

  short8 qs[8];
#pragma unroll
  for (int df = 0; df < 8; ++df){
    const float* p0 = Qh + (size_t)q0 * D + df*16 + h*8;
    float4 a = *(const float4*)(p0);
    float4 b = *(const float4*)(p0 + 4);
    union { u32 u[4]; short8 s; } cv;
    cv.u[0] = pkh(a.x, a.y); cv.u[1] = pkh(a.z, a.w);
    cv.u[2] = pkh(b.x, b.y); cv.u[3] = pkh(b.z, b.w);
    qs[df] = cv.s;
  }

  float4 kr[8], vr[8];
  int mpre = 1;
#pragma unroll
  for (int p = 0; p < 8; ++p){
    int row = p*8 + srow;
    kr[p] = *(const float4*)&Kh[(size_t)row * D + scol*4];
    vr[p] = *(const float4*)&Vh[(size_t)row * D + scol*4];
  }
  if (tid < 64) mpre = Mh[tid];

  f32x16 accO[4];
#pragma unroll
  for (int dn = 0; dn < 4; ++dn) accO[dn] = zero16();
  float mrun = -INFINITY, lrun = 0.0f;

  const u32 vbase = (u32)(size_t)(&Vlds[0]) + (u32)(h*2048 + b4*128 + r15*8);

  for (int t = 0; t < 32; ++t){
#pragma unroll
    for (int p = 0; p < 8; ++p){
      int row = p*8 + srow;
      u32 k0 = pkh(kr[p].x, kr[p].y), k1 = pkh(kr[p].z, kr[p].w);
      *(u64*)&Klds[row*136 + scol*4] = ((u64)k1 << 32) | k0;
      u32 v0 = pkh(vr[p].x, vr[p].y), v1 = pkh(vr[p].z, vr[p].w);
      int E = (row >> 2)*512 + (scol >> 2)*64 + (row & 3)*16 + (scol & 3)*4;
      *(u64*)&Vlds[E] = ((u64)v1 << 32) | v0;
    }
    if (tid < 64) Mlds[tid] = (mpre != 0) ? 1.0f : 0.0f;

    if (t < 31){
      const int kv0 = (t+1)*64;
#pragma unroll
      for (int p = 0; p < 8; ++p){
        int row = kv0 + p*8 + srow;
        kr[p] = *(const float4*)&Kh[(size_t)row * D + scol*4];
        vr[p] = *(const float4*)&Vh[(size_t)row * D + scol*4];
      }
      if (tid < 64) mpre = Mh[kv0 + tid];
    }

    sync_lds();

    f32x16 sa[2];
    sa[0] = zero16(); sa[1] = zero16();
#pragma unroll
    for (int mf = 0; mf < 2; ++mf){
#pragma unroll
      for (int df = 0; df < 8; ++df){
        short8 kf8 = *(const short8*)&Klds[(mf*32 + r31)*136 + df*16 + h*8];
        sa[mf] = __builtin_amdgcn_mfma_f32_32x32x16_f16(kf8, qs[df], sa[mf], 0, 0, 0);
      }
    }

    float pmax = -3.0e38f;
#pragma unroll
    for (int mf = 0; mf < 2; ++mf)
#pragma unroll
      for (int i = 0; i < 16; ++i) pmax = fmaxf(pmax, sa[mf][i]);
    pmax = fmaxf(pmax, __shfl_xor(pmax, 32, 64));
    const float mnew  = fmaxf(mrun, pmax);
    const float scale = __expf(mrun - mnew);
    float psum = 0.0f;
#pragma unroll
    for (int mf = 0; mf < 2; ++mf){
#pragma unroll
      for (int rb = 0; rb < 4; ++rb){
        float4 mv = *(const float4*)&Mlds[mf*32 + rb*8 + h*4];
        float mva[4] = {mv.x, mv.y, mv.z, mv.w};
#pragma unroll
        for (int i = 0; i < 4; ++i){
          float e = __expf(sa[mf][rb*4 + i] - mnew) * mva[i];
          sa[mf][rb*4 + i] = e;
          psum += e;
        }
      }
    }
    psum += __shfl_xor(psum, 32, 64);
    lrun = lrun * scale + psum;
    mrun = mnew;
#pragma unroll
    for (int dn = 0; dn < 4; ++dn)
#pragma unroll
      for (int i = 0; i < 16; ++i) accO[dn][i] *= scale;

    short8 pf8[4];
#pragma unroll
    for (int kf = 0; kf < 4; ++kf){
      const int mf = kf >> 1, o = (kf & 1)*8;
      u32 w0 = pkh(sa[mf][o+0], sa[mf][o+1]);
      u32 w1 = pkh(sa[mf][o+2], sa[mf][o+3]);
      u32 w2 = pkh(sa[mf][o+4], sa[mf][o+5]);
      u32 w3 = pkh(sa[mf][o+6], sa[mf][o+7]);
      u32 s0 = __shfl_xor(w0, 32, 64);
      u32 s1 = __shfl_xor(w1, 32, 64);
      u32 s2 = __shfl_xor(w2, 32, 64);
      u32 s3 = __shfl_xor(w3, 32, 64);
      union { u32 u[4]; short8 s; } cv;
      cv.u[0] = h ? s2 : w0;
      cv.u[1] = h ? s3 : w1;
      cv.u[2] = h ? w2 : s0;
      cv.u[3] = h ? w3 : s1;
      pf8[kf] = cv.s;
    }

#pragma unroll
    for (int dn = 0; dn < 4; ++dn){
      u32 vdn = vbase + dn*256;
      u64 ta0, ta1, tb0, tb1, tc0, tc1, td0, td1;
      TR_READ(ta0, vdn, "0");     TR_READ(ta1, vdn, "1024");
      TR_READ(tb0, vdn, "4096");  TR_READ(tb1, vdn, "5120");
      TR_READ(tc0, vdn, "8192");  TR_READ(tc1, vdn, "9216");
      TR_READ(td0, vdn, "12288"); TR_READ(td1, vdn, "13312");
      asm volatile("s_waitcnt lgkmcnt(0)" ::: "memory");
      __builtin_amdgcn_sched_barrier(0);
      union { u64 q[2]; short8 s; } fa, fb, fc, fd;
      fa.q[0] = ta0; fa.q[1] = ta1;
      fb.q[0] = tb0; fb.q[1] = tb1;
      fc.q[0] = tc0; fc.q[1] = tc1;
      fd.q[0] = td0; fd.q[1] = td1;
      accO[dn] = __builtin_amdgcn_mfma_f32_32x32x16_f16(fa.s, pf8[0], accO[dn], 0,0,0);
      accO[dn] = __builtin_amdgcn_mfma_f32_32x32x16_f16(fb.s, pf8[1], accO[dn], 0,0,0);
      accO[dn] = __builtin_amdgcn_mfma_f32_32x32x16_f16(fc.s, pf8[2], accO[dn], 0,0,0);
      accO[dn] = __builtin_amdgcn_mfma_f32_32x32x16_f16(fd.s, pf8[3], accO[dn], 0,0,0);
    }

    sync_lds();
  }

  const float inv = 1.0f / lrun;
  float* Orow = Oh + (size_t)q0 * D;
#pragma unroll
  for (int dn = 0; dn < 4; ++dn){
#pragma unroll
    for (int rb = 0; rb < 4; ++rb){
      float4 o4;
      o4.x = accO[dn][rb*4+0]*inv;
      o4.y = accO[dn][rb*4+1]*inv;
      o4.z = accO[dn][rb*4+2]*inv;
      o4.w = accO[dn][rb*4+3]*inv;
      *(float4*)&Orow[dn*32 + rb*8 + h*4] = o4;
    }
  }
}

extern "C" void kernel_launch(void* const* d_in, const int* in_sizes, int n_in,
                              void* d_out, int out_size, void* d_ws, size_t ws_size,
                              hipStream_t stream) {
  const float* q = (const float*)d_in[0];
  const float* k = (const float*)d_in[1];
  const float* v = (const float*)d_in[2];
  const int*   m = (const int*)d_in[3];
  float* out = (float*)d_out;
  if (ws_size >= WS_NEED){
    sdpa_prepass<<<dim3(BH_ * NT), dim3(256), 0, stream>>>(k, v, m, (char*)d_ws);
    sdpa_main<<<dim3(512), dim3(256), 0, stream>>>(q, (const char*)d_ws, out);
  } else {
    sdpa_fallback<<<dim3(1024), dim3(256), 0, stream>>>(q, k, v, m, out);
  }
}